// Round 6
// baseline (704.352 us; speedup 1.0000x reference)
//
#include <hip/hip_runtime.h>

typedef unsigned short u16;
typedef unsigned int u32;
typedef float f32x4 __attribute__((ext_vector_type(4)));
typedef __bf16 bf16x8 __attribute__((ext_vector_type(8)));

#define DEV __device__ __forceinline__

DEV u16 f2b(float f) {
    union { float f; u32 u; } v; v.f = f;
    u32 r = v.u + 0x7fffu + ((v.u >> 16) & 1u);   // RNE
    return (u16)(r >> 16);
}
DEV float b2f(u16 b) {
    union { u32 u; float f; } v; v.u = ((u32)b) << 16;
    return v.f;
}

// global -> LDS direct (16B/lane). LDS dest must be wave-uniform base; HW adds lane*16.
DEV void gload16(const void* g, void* l) {
    __builtin_amdgcn_global_load_lds((const __attribute__((address_space(1))) void*)g,
                                     (__attribute__((address_space(3))) void*)l, 16, 0, 0);
}

DEV f32x4 mfma16(bf16x8 a, bf16x8 b, f32x4 c) {
    return __builtin_amdgcn_mfma_f32_16x16x32_bf16(a, b, c, 0, 0, 0);
}

// ---------------------------------------------------------------- convert x
__global__ __launch_bounds__(256) void convx_kernel(const float* __restrict__ in,
                                                    u16* __restrict__ out) {
    size_t i = ((size_t)blockIdx.x * 256 + threadIdx.x) * 4;
    float4 v = *(const float4*)(in + i);
    ushort4 o; o.x = f2b(v.x); o.y = f2b(v.y); o.z = f2b(v.z); o.w = f2b(v.w);
    *(ushort4*)(out + i) = o;
}

// ------------------------------------------- transpose + convert: (KxN f32) -> (NxK bf16)
__global__ __launch_bounds__(256) void tconv_kernel(const float* __restrict__ in,
                                                    u16* __restrict__ out, int K, int N) {
    __shared__ float tile[64][65];
    int t = threadIdx.x;
    int n0 = blockIdx.x * 64, k0 = blockIdx.y * 64;
    int r = t >> 4, c4 = (t & 15) * 4;
#pragma unroll
    for (int i = 0; i < 4; ++i) {
        float4 v = *(const float4*)(in + (size_t)(k0 + i * 16 + r) * N + n0 + c4);
        tile[i * 16 + r][c4 + 0] = v.x; tile[i * 16 + r][c4 + 1] = v.y;
        tile[i * 16 + r][c4 + 2] = v.z; tile[i * 16 + r][c4 + 3] = v.w;
    }
    __syncthreads();
#pragma unroll
    for (int i = 0; i < 4; ++i) {
        int nn = i * 16 + r;
        ushort4 o;
        o.x = f2b(tile[c4 + 0][nn]); o.y = f2b(tile[c4 + 1][nn]);
        o.z = f2b(tile[c4 + 2][nn]); o.w = f2b(tile[c4 + 3][nn]);
        *(ushort4*)(out + (size_t)(n0 + nn) * K + k0 + c4) = o;
    }
}

// ---------------------------------------------------------------- 256x256 8-phase GEMM, v2
// Template-faithful rebuild: NO sched_barrier (m141: order-pinning cost 874->510 on m97),
// staging strictly 1 half-tile (2 gloads) per phase, K-loop manually unrolled x2 so the
// dbuf parity p is compile-time and all swizzled LDS addresses are loop-invariant.
// Staging schedule (per tile kt, buf p=kt&1): ph0 B0(kt+1), ph1 B1(kt+1) [slot Bsb[1-p]
// last read at kt-1 ph2], ph2 A0(kt+2), ph3 A1(kt+2) [slot Asb[p] last read at kt ph1].
// Boundary vmcnt(4) at ph3: retires B(kt+1) (4 older loads), leaves A(kt+2) in flight;
// A(kt+2) is retired by kt+1's vmcnt(4) before kt+2 reads it. Tail: kt==nk-2 -> vmcnt(0).
template <bool F32OUT>
__global__ __launch_bounds__(512, 2) void gemm256_kernel(const u16* __restrict__ A,
                                                         const u16* __restrict__ Bt,
                                                         u16* __restrict__ Cb,
                                                         float* __restrict__ Cf,
                                                         int N, int K, int gy) {
    __shared__ __align__(16) u16 Asb[2][2][128 * 64];
    __shared__ __align__(16) u16 Bsb[2][2][128 * 64];
    int t = threadIdx.x;
    int lane = t & 63, w = t >> 6;
    int wrM = w >> 2, wcN = w & 3;
    int lr = lane & 15, hi = lane >> 4;
    int wg = blockIdx.x;
    int swz = (wg & 7) * ((int)gridDim.x >> 3) + (wg >> 3);
    int bx = swz / gy, by = swz % gy;    // column-major raster: L2 panel sharing (r4)
    int m0 = by * 256, n0 = bx * 256;
    int nk = K >> 6;

    auto stageA = [&](int X, int h) {
        const u16* src = A + (size_t)(m0 + h * 128) * K + X * 64;
        char* dst = (char*)&Asb[X & 1][h][0];
#pragma unroll
        for (int it = 0; it < 2; ++it) {
            int c = it * 512 + t;
            int row = c >> 3;
            int col8 = ((c & 7) ^ (row & 7)) << 3;
            gload16(src + (size_t)row * K + col8, dst + (it * 512 + (t & ~63)) * 16);
        }
    };
    auto stageB = [&](int X, int h) {
        const u16* src = Bt + (size_t)(n0 + h * 128) * K + X * 64;
        char* dst = (char*)&Bsb[X & 1][h][0];
#pragma unroll
        for (int it = 0; it < 2; ++it) {
            int c = it * 512 + t;
            int row = c >> 3;
            int col8 = ((c & 7) ^ (row & 7)) << 3;
            gload16(src + (size_t)row * K + col8, dst + (it * 512 + (t & ~63)) * 16);
        }
    };

    // prologue: tile0 complete + A(1); vmcnt(4) -> tile0 landed, A(1) in flight
    stageA(0, 0); stageA(0, 1); stageB(0, 0); stageB(0, 1);
    stageA(1, 0); stageA(1, 1);
    asm volatile("s_waitcnt vmcnt(4)" ::: "memory");
    __builtin_amdgcn_s_barrier();

    f32x4 acc[8][4] = {};

    auto tile = [&](int kt, int p) __attribute__((always_inline)) {
        const char* Ah = (const char*)&Asb[p][wrM][0];
        const char* Bh = (const char*)&Bsb[p][wcN >> 1][0];
        bool sB = (kt + 1 < nk), sA = (kt + 2 < nk);
        bf16x8 a[8][2], bb[2][2];

        // ---- ph0: read a0-3 + b0-1; stage B0(kt+1); MFMA Q(0,0)
#pragma unroll
        for (int mf = 0; mf < 4; ++mf)
#pragma unroll
            for (int ks = 0; ks < 2; ++ks) {
                int row = mf * 16 + lr;
                a[mf][ks] = *(const bf16x8*)(Ah + ((row * 128 + ks * 64 + hi * 16) ^ ((row & 7) << 4)));
            }
#pragma unroll
        for (int nf = 0; nf < 2; ++nf)
#pragma unroll
            for (int ks = 0; ks < 2; ++ks) {
                int row = (wcN & 1) * 64 + nf * 16 + lr;
                bb[nf][ks] = *(const bf16x8*)(Bh + ((row * 128 + ks * 64 + hi * 16) ^ ((row & 7) << 4)));
            }
        if (sB) stageB(kt + 1, 0);
        __builtin_amdgcn_s_barrier();
        __builtin_amdgcn_s_setprio(1);
#pragma unroll
        for (int mf = 0; mf < 4; ++mf)
#pragma unroll
            for (int nf = 0; nf < 2; ++nf)
#pragma unroll
                for (int ks = 0; ks < 2; ++ks)
                    acc[mf][nf] = mfma16(a[mf][ks], bb[nf][ks], acc[mf][nf]);
        __builtin_amdgcn_s_setprio(0);
        __builtin_amdgcn_s_barrier();

        // ---- ph1: read a4-7; stage B1(kt+1); MFMA Q(1,0)
#pragma unroll
        for (int mf = 4; mf < 8; ++mf)
#pragma unroll
            for (int ks = 0; ks < 2; ++ks) {
                int row = mf * 16 + lr;
                a[mf][ks] = *(const bf16x8*)(Ah + ((row * 128 + ks * 64 + hi * 16) ^ ((row & 7) << 4)));
            }
        if (sB) stageB(kt + 1, 1);
        __builtin_amdgcn_s_barrier();
        __builtin_amdgcn_s_setprio(1);
#pragma unroll
        for (int mf = 4; mf < 8; ++mf)
#pragma unroll
            for (int nf = 0; nf < 2; ++nf)
#pragma unroll
                for (int ks = 0; ks < 2; ++ks)
                    acc[mf][nf] = mfma16(a[mf][ks], bb[nf][ks], acc[mf][nf]);
        __builtin_amdgcn_s_setprio(0);
        __builtin_amdgcn_s_barrier();

        // ---- ph2: read b2-3; stage A0(kt+2); MFMA Q(1,1)
#pragma unroll
        for (int nf = 0; nf < 2; ++nf)
#pragma unroll
            for (int ks = 0; ks < 2; ++ks) {
                int row = (wcN & 1) * 64 + (nf + 2) * 16 + lr;
                bb[nf][ks] = *(const bf16x8*)(Bh + ((row * 128 + ks * 64 + hi * 16) ^ ((row & 7) << 4)));
            }
        if (sA) stageA(kt + 2, 0);
        __builtin_amdgcn_s_barrier();
        __builtin_amdgcn_s_setprio(1);
#pragma unroll
        for (int mf = 4; mf < 8; ++mf)
#pragma unroll
            for (int nf = 0; nf < 2; ++nf)
#pragma unroll
                for (int ks = 0; ks < 2; ++ks)
                    acc[mf][nf + 2] = mfma16(a[mf][ks], bb[nf][ks], acc[mf][nf + 2]);
        __builtin_amdgcn_s_setprio(0);
        __builtin_amdgcn_s_barrier();

        // ---- ph3: stage A1(kt+2); MFMA Q(0,1); boundary vmcnt
        if (sA) stageA(kt + 2, 1);
        __builtin_amdgcn_s_barrier();
        __builtin_amdgcn_s_setprio(1);
#pragma unroll
        for (int mf = 0; mf < 4; ++mf)
#pragma unroll
            for (int nf = 0; nf < 2; ++nf)
#pragma unroll
                for (int ks = 0; ks < 2; ++ks)
                    acc[mf][nf + 2] = mfma16(a[mf][ks], bb[nf][ks], acc[mf][nf + 2]);
        __builtin_amdgcn_s_setprio(0);
        if (sA)      asm volatile("s_waitcnt vmcnt(4)" ::: "memory");  // B(kt+1) landed
        else if (sB) asm volatile("s_waitcnt vmcnt(0)" ::: "memory");  // tail: drain all
        __builtin_amdgcn_s_barrier();
    };

    for (int kt = 0; kt < nk; kt += 2) {   // nk even (K % 128 == 0)
        tile(kt, 0);
        tile(kt + 1, 1);
    }

    // epilogue
#pragma unroll
    for (int mf = 0; mf < 8; ++mf)
#pragma unroll
        for (int nf = 0; nf < 4; ++nf)
#pragma unroll
            for (int r = 0; r < 4; ++r) {
                int m = m0 + wrM * 128 + mf * 16 + hi * 4 + r;
                int n = n0 + wcN * 64 + nf * 16 + lr;
                if (F32OUT) Cf[(size_t)m * N + n] = acc[mf][nf][r];
                else        Cb[(size_t)m * N + n] = f2b(acc[mf][nf][r]);
            }
}

// ------------------------------- RoPE in-place on fused qkv (stride 6144) + roped-k f32 out
__global__ __launch_bounds__(256) void rope_kernel(u16* __restrict__ qkv,
                                                   float* __restrict__ outk) {
    int row = blockIdx.y;                    // b*2048 + l
    int p = blockIdx.x * 256 + threadIdx.x;  // 0..2559: 32 q-heads + 8 kv-heads, 64 pairs each
    int b = row >> 11, l = row & 2047;
    float freq = exp2f((float)(p & 63) * -0.2076205059304601f);  // 10000^(-i/64)
    float sv, cv; sincosf((float)l * freq, &sv, &cv);
    if (p < 2048) {
        int h = p >> 6, i = p & 63;
        size_t idx = (size_t)row * 6144 + h * 128 + 2 * i;
        u32 pr = *(const u32*)(qkv + idx);
        float x1 = b2f((u16)(pr & 0xffff)), x2 = b2f((u16)(pr >> 16));
        float o1 = x1 * cv + x2 * sv, o2 = x1 * sv - x2 * cv;
        *(u32*)(qkv + idx) = (u32)f2b(o1) | ((u32)f2b(o2) << 16);
    } else {
        int kvh = (p >> 6) - 32, i = p & 63;
        size_t idx = (size_t)row * 6144 + 4096 + kvh * 128 + 2 * i;
        u32 pr = *(const u32*)(qkv + idx);
        float x1 = b2f((u16)(pr & 0xffff)), x2 = b2f((u16)(pr >> 16));
        float o1 = x1 * cv + x2 * sv, o2 = x1 * sv - x2 * cv;
        *(u32*)(qkv + idx) = (u32)f2b(o1) | ((u32)f2b(o2) << 16);
#pragma unroll
        for (int r = 0; r < 4; ++r) {
            float2 o; o.x = o1; o.y = o2;
            *(float2*)(outk + ((size_t)((b * 32 + kvh * 4 + r) * 2048) + l) * 128 + 2 * i) = o;
        }
    }
}

// --------------------------------- V: write f32 x4 GQA copies to d_out + bf16 V^T for attention
__global__ __launch_bounds__(256) void vtrans_kernel(const u16* __restrict__ qkv,
                                                     u16* __restrict__ vt,
                                                     float* __restrict__ outv) {
    __shared__ u16 tile[64][65];
    int t = threadIdx.x;
    int l0 = blockIdx.x * 64, d0 = blockIdx.y * 64;
    int z = blockIdx.z, b = z >> 3, kvh = z & 7;
    int r = t >> 4, c4 = (t & 15) * 4;
#pragma unroll
    for (int i = 0; i < 4; ++i) {
        int l = l0 + i * 16 + r;
        ushort4 v = *(const ushort4*)(qkv + (size_t)(b * 2048 + l) * 6144 + 5120 + kvh * 128 + d0 + c4);
        tile[i * 16 + r][c4 + 0] = v.x; tile[i * 16 + r][c4 + 1] = v.y;
        tile[i * 16 + r][c4 + 2] = v.z; tile[i * 16 + r][c4 + 3] = v.w;
        float4 f; f.x = b2f(v.x); f.y = b2f(v.y); f.z = b2f(v.z); f.w = b2f(v.w);
#pragma unroll
        for (int rr = 0; rr < 4; ++rr)
            *(float4*)(outv + ((size_t)((b * 32 + kvh * 4 + rr) * 2048) + l) * 128 + d0 + c4) = f;
    }
    __syncthreads();
#pragma unroll
    for (int i = 0; i < 4; ++i) {
        int dn = i * 16 + r;
        ushort4 o;
        o.x = tile[c4 + 0][dn]; o.y = tile[c4 + 1][dn];
        o.z = tile[c4 + 2][dn]; o.w = tile[c4 + 3][dn];
        *(ushort4*)(vt + (size_t)((b * 8 + kvh) * 128 + d0 + dn) * 2048 + l0 + c4) = o;
    }
}

// ---------------------------------------------------------------- flash attention v2
__global__ __launch_bounds__(256) void attn_kernel(const u16* __restrict__ qkv,
                                                   const u16* __restrict__ vt,
                                                   u16* __restrict__ ab) {
    __shared__ __align__(16) u16 Kbuf[2][64 * 128];   // K tile [kv][dh]
    __shared__ __align__(16) u16 Vbuf[2][128 * 64];   // V^T tile [dh][kv]
    __shared__ __align__(16) u16 Ps[4][16 * 64];      // per-wave P
    int t = threadIdx.x, lane = t & 63, w = t >> 6;
    int lr = lane & 15, hi = lane >> 4;
    int h = blockIdx.y, b = blockIdx.z, kvh = h >> 2;

    const u16* kbase = qkv + (size_t)(b * 2048) * 6144 + 4096 + kvh * 128;
    const u16* vtbase = vt + (size_t)((b * 8 + kvh) * 128) * 2048;

    auto stageKV = [&](int k0, int buf) {
#pragma unroll
        for (int i = 0; i < 4; ++i) {   // K: 64 rows x 128 cols
            int c = i * 256 + t;
            int row = c >> 4;
            int col8 = ((c & 15) ^ (row & 7)) << 3;
            gload16(kbase + (size_t)(k0 + row) * 6144 + col8,
                    (char*)Kbuf[buf] + (i * 256 + (t & ~63)) * 16);
        }
#pragma unroll
        for (int i = 0; i < 4; ++i) {   // V^T: 128 rows x 64 cols
            int c = i * 256 + t;
            int row = c >> 3;
            int col8 = ((c & 7) ^ (row & 7)) << 3;
            gload16(vtbase + (size_t)row * 2048 + k0 + col8,
                    (char*)Vbuf[buf] + (i * 256 + (t & ~63)) * 16);
        }
    };

    auto process = [&](int qblk) {
        int q0 = qblk * 64;
        int qr = w * 16 + lr;
        bf16x8 qf[4];
#pragma unroll
        for (int kki = 0; kki < 4; ++kki)   // Q direct global->reg
            qf[kki] = *(const bf16x8*)(qkv + (size_t)(b * 2048 + q0 + qr) * 6144 + h * 128 +
                                       kki * 32 + 8 * hi);
        f32x4 acc[8] = {};
        float mrun[4], lrun[4];
#pragma unroll
        for (int r = 0; r < 4; ++r) { mrun[r] = -1e30f; lrun[r] = 0.f; }

        int nt = qblk + 1;
        stageKV(0, 0);
        __syncthreads();
        int cur = 0;
        for (int kt = 0; kt < nt; ++kt) {
            if (kt + 1 < nt) stageKV((kt + 1) * 64, cur ^ 1);  // prefetch next tile
            __builtin_amdgcn_sched_barrier(0);

            const u16* Ks = Kbuf[cur];
            const u16* Vs = Vbuf[cur];
            // S = Q K^T
            f32x4 s[4] = {};
            __builtin_amdgcn_s_setprio(1);
#pragma unroll
            for (int kki = 0; kki < 4; ++kki) {
                bf16x8 kf[4];
#pragma unroll
                for (int fc = 0; fc < 4; ++fc) {
                    int kvr = fc * 16 + lr;
                    int byt = (kvr * 256 + (kki * 32 + 8 * hi) * 2) ^ ((kvr & 7) << 4);
                    kf[fc] = *(const bf16x8*)((const char*)Ks + byt);
                }
#pragma unroll
                for (int fc = 0; fc < 4; ++fc) s[fc] = mfma16(qf[kki], kf[fc], s[fc]);
            }
            __builtin_amdgcn_s_setprio(0);
            const float SC = 0.08838834764831845f;  // 1/sqrt(128)
            int diag = (kt == nt - 1);
#pragma unroll
            for (int fc = 0; fc < 4; ++fc)
#pragma unroll
                for (int r = 0; r < 4; ++r) {
                    float v = s[fc][r] * SC;
                    if (diag && (fc * 16 + lr) > (w * 16 + hi * 4 + r)) v = -1e30f;
                    s[fc][r] = v;
                }
            // online softmax
            float fr[4];
#pragma unroll
            for (int r = 0; r < 4; ++r) {
                float v = fmaxf(fmaxf(s[0][r], s[1][r]), fmaxf(s[2][r], s[3][r]));
                v = fmaxf(v, __shfl_xor(v, 1)); v = fmaxf(v, __shfl_xor(v, 2));
                v = fmaxf(v, __shfl_xor(v, 4)); v = fmaxf(v, __shfl_xor(v, 8));
                float mn = fmaxf(mrun[r], v);
                fr[r] = __expf(mrun[r] - mn);
                mrun[r] = mn;
            }
#pragma unroll
            for (int fc = 0; fc < 4; ++fc)
#pragma unroll
                for (int r = 0; r < 4; ++r) s[fc][r] = __expf(s[fc][r] - mrun[r]);
#pragma unroll
            for (int r = 0; r < 4; ++r) {
                float v = s[0][r] + s[1][r] + s[2][r] + s[3][r];
                v += __shfl_xor(v, 1); v += __shfl_xor(v, 2);
                v += __shfl_xor(v, 4); v += __shfl_xor(v, 8);
                lrun[r] = lrun[r] * fr[r] + v;
            }
#pragma unroll
            for (int dhf = 0; dhf < 8; ++dhf)
#pragma unroll
                for (int r = 0; r < 4; ++r) acc[dhf][r] *= fr[r];
            // P -> LDS (bf16, swizzled)
            u16* Pw = Ps[w];
#pragma unroll
            for (int fc = 0; fc < 4; ++fc)
#pragma unroll
                for (int r = 0; r < 4; ++r) {
                    int prow = hi * 4 + r, pcol = fc * 16 + lr;
                    int byt = (prow * 128 + pcol * 2) ^ ((prow & 7) << 4);
                    *(u16*)((char*)Pw + byt) = f2b(s[fc][r]);
                }
            asm volatile("s_waitcnt lgkmcnt(0)" ::: "memory");
            // O += P V
            __builtin_amdgcn_s_setprio(1);
#pragma unroll
            for (int kk2 = 0; kk2 < 2; ++kk2) {
                int bytp = (lr * 128 + (kk2 * 32 + 8 * hi) * 2) ^ ((lr & 7) << 4);
                bf16x8 pf = *(const bf16x8*)((const char*)Pw + bytp);
#pragma unroll
                for (int dhf = 0; dhf < 8; ++dhf) {
                    int dh = dhf * 16 + lr;
                    int bytv = (dh * 128 + (kk2 * 32 + 8 * hi) * 2) ^ ((dh & 7) << 4);
                    bf16x8 vf = *(const bf16x8*)((const char*)Vs + bytv);
                    acc[dhf] = mfma16(pf, vf, acc[dhf]);
                }
            }
            __builtin_amdgcn_s_setprio(0);
            __syncthreads();   // drains vmcnt -> prefetched tile ready; buf[cur] reads retired
            cur ^= 1;
        }
        // epilogue
#pragma unroll
        for (int dhf = 0; dhf < 8; ++dhf)
#pragma unroll
            for (int r = 0; r < 4; ++r) {
                int qrow = q0 + w * 16 + hi * 4 + r;
                int dh = dhf * 16 + lr;
                ab[(size_t)(b * 2048 + qrow) * 4096 + h * 128 + dh] = f2b(acc[dhf][r] / lrun[r]);
            }
    };

    process(31 - blockIdx.x);   // long tile first
    __syncthreads();
    process(blockIdx.x);
}

// ---------------------------------------------------------------- launch
extern "C" void kernel_launch(void* const* d_in, const int* in_sizes, int n_in,
                              void* d_out, int out_size, void* d_ws, size_t ws_size,
                              hipStream_t stream) {
    (void)in_sizes; (void)n_in; (void)out_size; (void)ws_size;
    const float* x  = (const float*)d_in[0];
    // d_in[1] = mask: exact causal tril(0 / -1e9) — handled analytically in attn_kernel
    const float* wq = (const float*)d_in[2];
    const float* wk = (const float*)d_in[3];
    const float* wv = (const float*)d_in[4];
    const float* wo = (const float*)d_in[5];

    char* ws = (char*)d_ws;
    u16* xb  = (u16*)(ws + 0);                       // 32 MiB; reused as ab after QKV GEMM
    u16* fBt = (u16*)(ws + 33554432);                // 48 MiB fused [wq^T; wk^T; wv^T]
    u16* qkv = (u16*)(ws + 83886080);                // 48 MiB [4096][6144]
    u16* vt  = (u16*)(ws + 134217728);               //  8 MiB -> total 142 MiB
    u16* ab  = xb;
    u16* wob = fBt;                                  // reuse fBt region after QKV GEMM

    float* out0 = (float*)d_out;
    float* outk = out0 + 16777216;
    float* outv = out0 + 33554432;

    convx_kernel<<<16384, 256, 0, stream>>>(x, xb);
    tconv_kernel<<<dim3(64, 64), 256, 0, stream>>>(wq, fBt, 4096, 4096);
    tconv_kernel<<<dim3(16, 64), 256, 0, stream>>>(wk, fBt + (size_t)4096 * 4096, 4096, 1024);
    tconv_kernel<<<dim3(16, 64), 256, 0, stream>>>(wv, fBt + (size_t)5120 * 4096, 4096, 1024);

    // fused QKV projection: [4096 x 4096] @ [4096 x 6144] -> qkv (grid 24x16 = 384, %8==0)
    gemm256_kernel<false><<<384, 512, 0, stream>>>(xb, fBt, qkv, nullptr, 6144, 4096, 16);

    tconv_kernel<<<dim3(64, 64), 256, 0, stream>>>(wo, wob, 4096, 4096);  // fBt dead now

    rope_kernel<<<dim3(10, 4096), 256, 0, stream>>>(qkv, outk);
    vtrans_kernel<<<dim3(32, 2, 16), 256, 0, stream>>>(qkv, vt, outv);

    attn_kernel<<<dim3(16, 32, 2), 256, 0, stream>>>(qkv, vt, ab);

    // output projection: [4096 x 4096] @ [4096 x 4096] -> out0 f32 (grid 16x16 = 256, 1/CU)
    gemm256_kernel<true><<<256, 512, 0, stream>>>(ab, wob, nullptr, out0, 4096, 4096, 16);
}

// Round 7
// 616.523 us; speedup vs baseline: 1.1425x; 1.1425x over previous
//
#include <hip/hip_runtime.h>

typedef unsigned short u16;
typedef unsigned int u32;
typedef float f32x4 __attribute__((ext_vector_type(4)));
typedef u32 u32x2 __attribute__((ext_vector_type(2)));
typedef __bf16 bf16x8 __attribute__((ext_vector_type(8)));

#define DEV __device__ __forceinline__

DEV u16 f2b(float f) {
    union { float f; u32 u; } v; v.f = f;
    u32 r = v.u + 0x7fffu + ((v.u >> 16) & 1u);   // RNE
    return (u16)(r >> 16);
}
DEV float b2f(u16 b) {
    union { u32 u; float f; } v; v.u = ((u32)b) << 16;
    return v.f;
}

// global -> LDS direct (16B/lane). LDS dest must be wave-uniform base; HW adds lane*16.
DEV void gload16(const void* g, void* l) {
    __builtin_amdgcn_global_load_lds((const __attribute__((address_space(1))) void*)g,
                                     (__attribute__((address_space(3))) void*)l, 16, 0, 0);
}

DEV f32x4 mfma16(bf16x8 a, bf16x8 b, f32x4 c) {
    return __builtin_amdgcn_mfma_f32_16x16x32_bf16(a, b, c, 0, 0, 0);
}

// ---------------------------------------------------------------- convert x
__global__ __launch_bounds__(256) void convx_kernel(const float* __restrict__ in,
                                                    u16* __restrict__ out) {
    size_t i = ((size_t)blockIdx.x * 256 + threadIdx.x) * 4;
    float4 v = *(const float4*)(in + i);
    ushort4 o; o.x = f2b(v.x); o.y = f2b(v.y); o.z = f2b(v.z); o.w = f2b(v.w);
    *(ushort4*)(out + i) = o;
}

// ------------------------------------------- transpose + convert: (KxN f32) -> (NxK bf16)
__global__ __launch_bounds__(256) void tconv_kernel(const float* __restrict__ in,
                                                    u16* __restrict__ out, int K, int N) {
    __shared__ float tile[64][65];
    int t = threadIdx.x;
    int n0 = blockIdx.x * 64, k0 = blockIdx.y * 64;
    int r = t >> 4, c4 = (t & 15) * 4;
#pragma unroll
    for (int i = 0; i < 4; ++i) {
        float4 v = *(const float4*)(in + (size_t)(k0 + i * 16 + r) * N + n0 + c4);
        tile[i * 16 + r][c4 + 0] = v.x; tile[i * 16 + r][c4 + 1] = v.y;
        tile[i * 16 + r][c4 + 2] = v.z; tile[i * 16 + r][c4 + 3] = v.w;
    }
    __syncthreads();
#pragma unroll
    for (int i = 0; i < 4; ++i) {
        int nn = i * 16 + r;
        ushort4 o;
        o.x = f2b(tile[c4 + 0][nn]); o.y = f2b(tile[c4 + 1][nn]);
        o.z = f2b(tile[c4 + 2][nn]); o.w = f2b(tile[c4 + 3][nn]);
        *(ushort4*)(out + (size_t)(n0 + nn) * K + k0 + c4) = o;
    }
}

// ---------------------------------------------------------------- 256x192 4-phase GEMM (QKV)
// r5 measured-best for QKV: 242 us = 851 TF. Grid 16x32 = 512 blocks (2 clean rounds at
// 1 block/CU, LDS 112 KiB). See r5 notes for the staging race-freedom proof.
__global__ __launch_bounds__(512, 1) void gemm192_kernel(const u16* __restrict__ A,
                                                         const u16* __restrict__ Bt,
                                                         u16* __restrict__ Cb,
                                                         int N, int K, int gy) {
    __shared__ __align__(16) u16 Asb[2][2][128 * 64];
    __shared__ __align__(16) u16 Bsb[2][192 * 64];
    int t = threadIdx.x;
    int lane = t & 63, w = t >> 6;
    int wrM = w >> 2, wcN = w & 3;
    int lr = lane & 15, hi = lane >> 4;
    int wg = blockIdx.x;
    int swz = (wg & 7) * ((int)gridDim.x >> 3) + (wg >> 3);
    int bx = swz / gy, by = swz % gy;    // column-major raster for L2 panel sharing
    int m0 = by * 256, n0 = bx * 192;
    int nk = K >> 6;

    auto stageA = [&](int X) {           // 256 rows x 64 cols, 4 passes
        const u16* src = A + (size_t)m0 * K + X * 64;
        char* dst = (char*)&Asb[X & 1][0][0];
#pragma unroll
        for (int it = 0; it < 4; ++it) {
            int c = it * 512 + t;
            int row = c >> 3;
            int col8 = ((c & 7) ^ (row & 7)) << 3;
            gload16(src + (size_t)row * K + col8, dst + (it * 512 + (t & ~63)) * 16);
        }
    };
    auto stageB = [&](int X) {           // 192 rows x 64 cols, 3 passes
        const u16* src = Bt + (size_t)n0 * K + X * 64;
        char* dst = (char*)&Bsb[X & 1][0];
#pragma unroll
        for (int it = 0; it < 3; ++it) {
            int c = it * 512 + t;
            int row = c >> 3;
            int col8 = ((c & 7) ^ (row & 7)) << 3;
            gload16(src + (size_t)row * K + col8, dst + (it * 512 + (t & ~63)) * 16);
        }
    };

    stageA(0); stageB(0); stageA(1); stageB(1);
    asm volatile("s_waitcnt vmcnt(7)" ::: "memory");   // tile0 landed
    __builtin_amdgcn_s_barrier();

    f32x4 acc[8][3] = {};
    for (int kt = 0; kt < nk; ++kt) {
        __builtin_amdgcn_sched_barrier(0);
        int p = kt & 1;
        const char* Ah = (const char*)&Asb[p][wrM][0];
        const char* Bh = (const char*)&Bsb[p][0];
        bool s1 = (kt + 1 < nk), s2 = (kt + 2 < nk);
        bf16x8 a[8][2], bb[2][2], bc[2];

        // ---- ph0
#pragma unroll
        for (int mf = 0; mf < 4; ++mf)
#pragma unroll
            for (int ks = 0; ks < 2; ++ks) {
                int row = mf * 16 + lr;
                a[mf][ks] = *(const bf16x8*)(Ah + ((row * 128 + ks * 64 + hi * 16) ^ ((row & 7) << 4)));
            }
#pragma unroll
        for (int nf = 0; nf < 2; ++nf)
#pragma unroll
            for (int ks = 0; ks < 2; ++ks) {
                int row = wcN * 48 + nf * 16 + lr;
                bb[nf][ks] = *(const bf16x8*)(Bh + ((row * 128 + ks * 64 + hi * 16) ^ ((row & 7) << 4)));
            }
        __builtin_amdgcn_s_barrier();
        __builtin_amdgcn_s_setprio(1);
#pragma unroll
        for (int mf = 0; mf < 4; ++mf)
#pragma unroll
            for (int nf = 0; nf < 2; ++nf)
#pragma unroll
                for (int ks = 0; ks < 2; ++ks)
                    acc[mf][nf] = mfma16(a[mf][ks], bb[nf][ks], acc[mf][nf]);
        __builtin_amdgcn_s_setprio(0);
        __builtin_amdgcn_s_barrier();

        // ---- ph1
#pragma unroll
        for (int mf = 4; mf < 8; ++mf)
#pragma unroll
            for (int ks = 0; ks < 2; ++ks) {
                int row = mf * 16 + lr;
                a[mf][ks] = *(const bf16x8*)(Ah + ((row * 128 + ks * 64 + hi * 16) ^ ((row & 7) << 4)));
            }
        __builtin_amdgcn_s_barrier();
        __builtin_amdgcn_s_setprio(1);
#pragma unroll
        for (int mf = 4; mf < 8; ++mf)
#pragma unroll
            for (int nf = 0; nf < 2; ++nf)
#pragma unroll
                for (int ks = 0; ks < 2; ++ks)
                    acc[mf][nf] = mfma16(a[mf][ks], bb[nf][ks], acc[mf][nf]);
        __builtin_amdgcn_s_setprio(0);
        __builtin_amdgcn_s_barrier();

        // ---- ph2: stage A(kt+2)
#pragma unroll
        for (int ks = 0; ks < 2; ++ks) {
            int row = wcN * 48 + 32 + lr;
            bc[ks] = *(const bf16x8*)(Bh + ((row * 128 + ks * 64 + hi * 16) ^ ((row & 7) << 4)));
        }
        if (s2) stageA(kt + 2);
        __builtin_amdgcn_s_barrier();
        __builtin_amdgcn_s_setprio(1);
#pragma unroll
        for (int mf = 4; mf < 8; ++mf)
#pragma unroll
            for (int ks = 0; ks < 2; ++ks)
                acc[mf][2] = mfma16(a[mf][ks], bc[ks], acc[mf][2]);
        __builtin_amdgcn_s_setprio(0);
        __builtin_amdgcn_s_barrier();

        // ---- ph3: stage B(kt+2); boundary vmcnt
        if (s2) stageB(kt + 2);
        __builtin_amdgcn_s_barrier();
        __builtin_amdgcn_s_setprio(1);
#pragma unroll
        for (int mf = 0; mf < 4; ++mf)
#pragma unroll
            for (int ks = 0; ks < 2; ++ks)
                acc[mf][2] = mfma16(a[mf][ks], bc[ks], acc[mf][2]);
        __builtin_amdgcn_s_setprio(0);
        if (s1) {
            if (s2) asm volatile("s_waitcnt vmcnt(7)" ::: "memory");
            else    asm volatile("s_waitcnt vmcnt(0)" ::: "memory");
        }
        __builtin_amdgcn_s_barrier();
    }

#pragma unroll
    for (int mf = 0; mf < 8; ++mf)
#pragma unroll
        for (int nf = 0; nf < 3; ++nf)
#pragma unroll
            for (int r = 0; r < 4; ++r) {
                int m = m0 + wrM * 128 + mf * 16 + hi * 4 + r;
                int n = n0 + wcN * 48 + nf * 16 + lr;
                Cb[(size_t)m * N + n] = f2b(acc[mf][nf][r]);
            }
}

// ---------------------------------------------------------------- 256x256 8-phase GEMM (WO)
template <bool F32OUT>
__global__ __launch_bounds__(512, 1) void gemm256_kernel(const u16* __restrict__ A,
                                                         const u16* __restrict__ Bt,
                                                         u16* __restrict__ Cb,
                                                         float* __restrict__ Cf,
                                                         int M, int N, int K, int gy) {
    __shared__ __align__(16) u16 Asb[2][2][128 * 64];
    __shared__ __align__(16) u16 Bsb[2][2][128 * 64];
    (void)M;
    int t = threadIdx.x;
    int lane = t & 63, w = t >> 6;
    int wrM = w >> 2, wcN = w & 3;
    int lr = lane & 15, hi = lane >> 4;
    int wg = blockIdx.x;
    int swz = (wg & 7) * ((int)gridDim.x >> 3) + (wg >> 3);
    int bx = swz / gy, by = swz % gy;
    int m0 = by * 256, n0 = bx * 256;
    int nk = K >> 6;

    auto stageA = [&](int X, int h) {
        const u16* src = A + (size_t)(m0 + h * 128) * K + X * 64;
        char* dst = (char*)&Asb[X & 1][h][0];
#pragma unroll
        for (int it = 0; it < 2; ++it) {
            int c = it * 512 + t;
            int row = c >> 3;
            int col8 = ((c & 7) ^ (row & 7)) << 3;
            gload16(src + (size_t)row * K + col8, dst + (it * 512 + (t & ~63)) * 16);
        }
    };
    auto stageB = [&](int X, int h) {
        const u16* src = Bt + (size_t)(n0 + h * 128) * K + X * 64;
        char* dst = (char*)&Bsb[X & 1][h][0];
#pragma unroll
        for (int it = 0; it < 2; ++it) {
            int c = it * 512 + t;
            int row = c >> 3;
            int col8 = ((c & 7) ^ (row & 7)) << 3;
            gload16(src + (size_t)row * K + col8, dst + (it * 512 + (t & ~63)) * 16);
        }
    };

    stageA(0, 0); stageA(0, 1); stageB(0, 0); stageB(0, 1);
    stageA(1, 0); stageA(1, 1); stageB(1, 0);
    asm volatile("s_waitcnt vmcnt(6)" ::: "memory");
    __builtin_amdgcn_s_barrier();

    f32x4 acc[8][4] = {};
    for (int kt = 0; kt < nk; ++kt) {
        __builtin_amdgcn_sched_barrier(0);
        int p = kt & 1;
        const char* Ah = (const char*)&Asb[p][wrM][0];
        const char* Bh = (const char*)&Bsb[p][wcN >> 1][0];
        bool s1 = (kt + 1 < nk), s2 = (kt + 2 < nk);
        bf16x8 a[8][2], bb[2][2];

        // ---- ph0
#pragma unroll
        for (int mf = 0; mf < 4; ++mf)
#pragma unroll
            for (int ks = 0; ks < 2; ++ks) {
                int row = mf * 16 + lr;
                a[mf][ks] = *(const bf16x8*)(Ah + ((row * 128 + ks * 64 + hi * 16) ^ ((row & 7) << 4)));
            }
#pragma unroll
        for (int nf = 0; nf < 2; ++nf)
#pragma unroll
            for (int ks = 0; ks < 2; ++ks) {
                int row = (wcN & 1) * 64 + nf * 16 + lr;
                bb[nf][ks] = *(const bf16x8*)(Bh + ((row * 128 + ks * 64 + hi * 16) ^ ((row & 7) << 4)));
            }
        if (s1) stageB(kt + 1, 1);
        __builtin_amdgcn_s_barrier();
        __builtin_amdgcn_s_setprio(1);
#pragma unroll
        for (int mf = 0; mf < 4; ++mf)
#pragma unroll
            for (int nf = 0; nf < 2; ++nf)
#pragma unroll
                for (int ks = 0; ks < 2; ++ks)
                    acc[mf][nf] = mfma16(a[mf][ks], bb[nf][ks], acc[mf][nf]);
        __builtin_amdgcn_s_setprio(0);
        __builtin_amdgcn_s_barrier();

        // ---- ph1
#pragma unroll
        for (int mf = 4; mf < 8; ++mf)
#pragma unroll
            for (int ks = 0; ks < 2; ++ks) {
                int row = mf * 16 + lr;
                a[mf][ks] = *(const bf16x8*)(Ah + ((row * 128 + ks * 64 + hi * 16) ^ ((row & 7) << 4)));
            }
        __builtin_amdgcn_s_barrier();
        __builtin_amdgcn_s_setprio(1);
#pragma unroll
        for (int mf = 4; mf < 8; ++mf)
#pragma unroll
            for (int nf = 0; nf < 2; ++nf)
#pragma unroll
                for (int ks = 0; ks < 2; ++ks)
                    acc[mf][nf] = mfma16(a[mf][ks], bb[nf][ks], acc[mf][nf]);
        __builtin_amdgcn_s_setprio(0);
        __builtin_amdgcn_s_barrier();

        // ---- ph2
#pragma unroll
        for (int nf = 0; nf < 2; ++nf)
#pragma unroll
            for (int ks = 0; ks < 2; ++ks) {
                int row = (wcN & 1) * 64 + (nf + 2) * 16 + lr;
                bb[nf][ks] = *(const bf16x8*)(Bh + ((row * 128 + ks * 64 + hi * 16) ^ ((row & 7) << 4)));
            }
        if (s2) { stageA(kt + 2, 0); stageA(kt + 2, 1); }
        __builtin_amdgcn_s_barrier();
        __builtin_amdgcn_s_setprio(1);
#pragma unroll
        for (int mf = 4; mf < 8; ++mf)
#pragma unroll
            for (int nf = 0; nf < 2; ++nf)
#pragma unroll
                for (int ks = 0; ks < 2; ++ks)
                    acc[mf][nf + 2] = mfma16(a[mf][ks], bb[nf][ks], acc[mf][nf + 2]);
        __builtin_amdgcn_s_setprio(0);
        __builtin_amdgcn_s_barrier();

        // ---- ph3
        if (s2) stageB(kt + 2, 0);
        __builtin_amdgcn_s_barrier();
        __builtin_amdgcn_s_setprio(1);
#pragma unroll
        for (int mf = 0; mf < 4; ++mf)
#pragma unroll
            for (int nf = 0; nf < 2; ++nf)
#pragma unroll
                for (int ks = 0; ks < 2; ++ks)
                    acc[mf][nf + 2] = mfma16(a[mf][ks], bb[nf][ks], acc[mf][nf + 2]);
        __builtin_amdgcn_s_setprio(0);
        if (s1) {
            if (s2) asm volatile("s_waitcnt vmcnt(6)" ::: "memory");
            else    asm volatile("s_waitcnt vmcnt(0)" ::: "memory");
        }
        __builtin_amdgcn_s_barrier();
    }

#pragma unroll
    for (int mf = 0; mf < 8; ++mf)
#pragma unroll
        for (int nf = 0; nf < 4; ++nf)
#pragma unroll
            for (int r = 0; r < 4; ++r) {
                int m = m0 + wrM * 128 + mf * 16 + hi * 4 + r;
                int n = n0 + wcN * 64 + nf * 16 + lr;
                if (F32OUT) Cf[(size_t)m * N + n] = acc[mf][nf][r];
                else        Cb[(size_t)m * N + n] = f2b(acc[mf][nf][r]);
            }
}

// ------------------------------- RoPE in-place on fused qkv (stride 6144) + roped-k f32 out
__global__ __launch_bounds__(256) void rope_kernel(u16* __restrict__ qkv,
                                                   float* __restrict__ outk) {
    int row = blockIdx.y;                    // b*2048 + l
    int p = blockIdx.x * 256 + threadIdx.x;  // 0..2559: 32 q-heads + 8 kv-heads, 64 pairs each
    int b = row >> 11, l = row & 2047;
    float freq = exp2f((float)(p & 63) * -0.2076205059304601f);  // 10000^(-i/64)
    float sv, cv; sincosf((float)l * freq, &sv, &cv);
    if (p < 2048) {
        int h = p >> 6, i = p & 63;
        size_t idx = (size_t)row * 6144 + h * 128 + 2 * i;
        u32 pr = *(const u32*)(qkv + idx);
        float x1 = b2f((u16)(pr & 0xffff)), x2 = b2f((u16)(pr >> 16));
        float o1 = x1 * cv + x2 * sv, o2 = x1 * sv - x2 * cv;
        *(u32*)(qkv + idx) = (u32)f2b(o1) | ((u32)f2b(o2) << 16);
    } else {
        int kvh = (p >> 6) - 32, i = p & 63;
        size_t idx = (size_t)row * 6144 + 4096 + kvh * 128 + 2 * i;
        u32 pr = *(const u32*)(qkv + idx);
        float x1 = b2f((u16)(pr & 0xffff)), x2 = b2f((u16)(pr >> 16));
        float o1 = x1 * cv + x2 * sv, o2 = x1 * sv - x2 * cv;
        *(u32*)(qkv + idx) = (u32)f2b(o1) | ((u32)f2b(o2) << 16);
#pragma unroll
        for (int r = 0; r < 4; ++r) {
            float2 o; o.x = o1; o.y = o2;
            *(float2*)(outk + ((size_t)((b * 32 + kvh * 4 + r) * 2048) + l) * 128 + 2 * i) = o;
        }
    }
}

// --------------------------------- V: write f32 x4 GQA copies to d_out + bf16 V^T for attention
__global__ __launch_bounds__(256) void vtrans_kernel(const u16* __restrict__ qkv,
                                                     u16* __restrict__ vt,
                                                     float* __restrict__ outv) {
    __shared__ u16 tile[64][65];
    int t = threadIdx.x;
    int l0 = blockIdx.x * 64, d0 = blockIdx.y * 64;
    int z = blockIdx.z, b = z >> 3, kvh = z & 7;
    int r = t >> 4, c4 = (t & 15) * 4;
#pragma unroll
    for (int i = 0; i < 4; ++i) {
        int l = l0 + i * 16 + r;
        ushort4 v = *(const ushort4*)(qkv + (size_t)(b * 2048 + l) * 6144 + 5120 + kvh * 128 + d0 + c4);
        tile[i * 16 + r][c4 + 0] = v.x; tile[i * 16 + r][c4 + 1] = v.y;
        tile[i * 16 + r][c4 + 2] = v.z; tile[i * 16 + r][c4 + 3] = v.w;
        float4 f; f.x = b2f(v.x); f.y = b2f(v.y); f.z = b2f(v.z); f.w = b2f(v.w);
#pragma unroll
        for (int rr = 0; rr < 4; ++rr)
            *(float4*)(outv + ((size_t)((b * 32 + kvh * 4 + rr) * 2048) + l) * 128 + d0 + c4) = f;
    }
    __syncthreads();
#pragma unroll
    for (int i = 0; i < 4; ++i) {
        int dn = i * 16 + r;
        ushort4 o;
        o.x = tile[c4 + 0][dn]; o.y = tile[c4 + 1][dn];
        o.z = tile[c4 + 2][dn]; o.w = tile[c4 + 3][dn];
        *(ushort4*)(vt + (size_t)((b * 8 + kvh) * 128 + d0 + dn) * 2048 + l0 + c4) = o;
    }
}

// ---------------------------------------------------------------- flash attention v3
// Swapped QK^T (S^T = mfma(K,Q)): each lane owns ONE q-row (q = w*16+lr); its 16 S values
// sit at kv = fc*16 + hi*4 + r. Softmax: 15 in-reg fmax + 2 shfl_xor(16,32); scalar m/l.
// P packed per-fc as one b64 LDS write (kv consecutive in r). PV = mfma(V^T_frag, P_frag):
// acc[dhf][r] = O[dh = dhf*16+hi*4+r][q]; epilogue = 8 ushort4 stores.
__global__ __launch_bounds__(256) void attn_kernel(const u16* __restrict__ qkv,
                                                   const u16* __restrict__ vt,
                                                   u16* __restrict__ ab) {
    __shared__ __align__(16) u16 Kbuf[2][64 * 128];   // K tile [kv][dh]
    __shared__ __align__(16) u16 Vbuf[2][128 * 64];   // V^T tile [dh][kv]
    __shared__ __align__(16) u16 Ps[4][16 * 64];      // per-wave P [q=16][kv=64]
    int t = threadIdx.x, lane = t & 63, w = t >> 6;
    int lr = lane & 15, hi = lane >> 4;
    int h = blockIdx.y, b = blockIdx.z, kvh = h >> 2;

    const u16* kbase = qkv + (size_t)(b * 2048) * 6144 + 4096 + kvh * 128;
    const u16* vtbase = vt + (size_t)((b * 8 + kvh) * 128) * 2048;

    auto stageKV = [&](int k0, int buf) {
#pragma unroll
        for (int i = 0; i < 4; ++i) {   // K: 64 rows x 128 cols
            int c = i * 256 + t;
            int row = c >> 4;
            int col8 = ((c & 15) ^ (row & 7)) << 3;
            gload16(kbase + (size_t)(k0 + row) * 6144 + col8,
                    (char*)Kbuf[buf] + (i * 256 + (t & ~63)) * 16);
        }
#pragma unroll
        for (int i = 0; i < 4; ++i) {   // V^T: 128 rows x 64 cols
            int c = i * 256 + t;
            int row = c >> 3;
            int col8 = ((c & 7) ^ (row & 7)) << 3;
            gload16(vtbase + (size_t)row * 2048 + k0 + col8,
                    (char*)Vbuf[buf] + (i * 256 + (t & ~63)) * 16);
        }
    };

    auto process = [&](int qblk) {
        int q0 = qblk * 64;
        int qr = w * 16 + lr;           // this lane's q-row (local to 64-block)
        bf16x8 qf[4];
#pragma unroll
        for (int kki = 0; kki < 4; ++kki)   // Q direct global->reg (B-operand frag)
            qf[kki] = *(const bf16x8*)(qkv + (size_t)(b * 2048 + q0 + qr) * 6144 + h * 128 +
                                       kki * 32 + 8 * hi);
        f32x4 acc[8] = {};
        float mrun = -1e30f, lrun = 0.f;

        int nt = qblk + 1;
        stageKV(0, 0);
        __syncthreads();
        int cur = 0;
        for (int kt = 0; kt < nt; ++kt) {
            if (kt + 1 < nt) stageKV((kt + 1) * 64, cur ^ 1);  // prefetch next tile
            __builtin_amdgcn_sched_barrier(0);

            const u16* Ks = Kbuf[cur];
            const u16* Vs = Vbuf[cur];
            // S^T = K Q^T  (A = K frag, B = Q frag)
            f32x4 s[4] = {};
            __builtin_amdgcn_s_setprio(1);
#pragma unroll
            for (int kki = 0; kki < 4; ++kki) {
                bf16x8 kf[4];
#pragma unroll
                for (int fc = 0; fc < 4; ++fc) {
                    int kvr = fc * 16 + lr;
                    int byt = (kvr * 256 + (kki * 32 + 8 * hi) * 2) ^ ((kvr & 7) << 4);
                    kf[fc] = *(const bf16x8*)((const char*)Ks + byt);
                }
#pragma unroll
                for (int fc = 0; fc < 4; ++fc) s[fc] = mfma16(kf[fc], qf[kki], s[fc]);
            }
            __builtin_amdgcn_s_setprio(0);
            const float SC = 0.08838834764831845f;  // 1/sqrt(128)
            int diag = (kt == nt - 1);
#pragma unroll
            for (int fc = 0; fc < 4; ++fc)
#pragma unroll
                for (int r = 0; r < 4; ++r) {
                    float v = s[fc][r] * SC;
                    if (diag && (fc * 16 + hi * 4 + r) > qr) v = -1e30f;  // kv > q
                    s[fc][r] = v;
                }
            // online softmax, scalar per lane (one q-row)
            float pm = s[0][0];
#pragma unroll
            for (int fc = 0; fc < 4; ++fc)
#pragma unroll
                for (int r = 0; r < 4; ++r) pm = fmaxf(pm, s[fc][r]);
            pm = fmaxf(pm, __shfl_xor(pm, 16));
            pm = fmaxf(pm, __shfl_xor(pm, 32));
            float mn = fmaxf(mrun, pm);
            float fr = __expf(mrun - mn);
            mrun = mn;
            float ls = 0.f;
#pragma unroll
            for (int fc = 0; fc < 4; ++fc)
#pragma unroll
                for (int r = 0; r < 4; ++r) {
                    float e = __expf(s[fc][r] - mn);
                    s[fc][r] = e;
                    ls += e;
                }
            ls += __shfl_xor(ls, 16);
            ls += __shfl_xor(ls, 32);
            lrun = lrun * fr + ls;
#pragma unroll
            for (int dhf = 0; dhf < 8; ++dhf)
#pragma unroll
                for (int r = 0; r < 4; ++r) acc[dhf][r] *= fr;
            // P -> LDS: per fc one b64 (4 bf16, kv consecutive), row q=lr, swizzled
            u16* Pw = Ps[w];
#pragma unroll
            for (int fc = 0; fc < 4; ++fc) {
                u32x2 pk;
                pk.x = (u32)f2b(s[fc][0]) | ((u32)f2b(s[fc][1]) << 16);
                pk.y = (u32)f2b(s[fc][2]) | ((u32)f2b(s[fc][3]) << 16);
                int byt = (lr * 128 + fc * 32 + hi * 8) ^ ((lr & 7) << 4);
                *(u32x2*)((char*)Pw + byt) = pk;
            }
            asm volatile("s_waitcnt lgkmcnt(0)" ::: "memory");
            // O^T += V^T P^T  (A = V^T frag, B = P frag)
            __builtin_amdgcn_s_setprio(1);
#pragma unroll
            for (int kk2 = 0; kk2 < 2; ++kk2) {
                int bytp = (lr * 128 + kk2 * 64 + hi * 16) ^ ((lr & 7) << 4);
                bf16x8 pf = *(const bf16x8*)((const char*)Pw + bytp);
#pragma unroll
                for (int dhf = 0; dhf < 8; ++dhf) {
                    int dh = dhf * 16 + lr;
                    int bytv = (dh * 128 + (kk2 * 32 + 8 * hi) * 2) ^ ((dh & 7) << 4);
                    bf16x8 vf = *(const bf16x8*)((const char*)Vs + bytv);
                    acc[dhf] = mfma16(vf, pf, acc[dhf]);
                }
            }
            __builtin_amdgcn_s_setprio(0);
            __syncthreads();   // drains vmcnt -> prefetched tile ready; buf[cur] reads retired
            cur ^= 1;
        }
        // epilogue: acc[dhf][r] = O[dh=dhf*16+hi*4+r][q=q0+qr]; pack 4 per store
        float inv = 1.0f / lrun;
        int qrow = q0 + qr;
#pragma unroll
        for (int dhf = 0; dhf < 8; ++dhf) {
            ushort4 o;
            o.x = f2b(acc[dhf][0] * inv); o.y = f2b(acc[dhf][1] * inv);
            o.z = f2b(acc[dhf][2] * inv); o.w = f2b(acc[dhf][3] * inv);
            *(ushort4*)(ab + (size_t)(b * 2048 + qrow) * 4096 + h * 128 + dhf * 16 + hi * 4) = o;
        }
    };

    process(31 - blockIdx.x);   // long tile first
    __syncthreads();
    process(blockIdx.x);
}

// ---------------------------------------------------------------- launch
extern "C" void kernel_launch(void* const* d_in, const int* in_sizes, int n_in,
                              void* d_out, int out_size, void* d_ws, size_t ws_size,
                              hipStream_t stream) {
    (void)in_sizes; (void)n_in; (void)out_size; (void)ws_size;
    const float* x  = (const float*)d_in[0];
    // d_in[1] = mask: exact causal tril(0 / -1e9) — handled analytically in attn_kernel
    const float* wq = (const float*)d_in[2];
    const float* wk = (const float*)d_in[3];
    const float* wv = (const float*)d_in[4];
    const float* wo = (const float*)d_in[5];

    char* ws = (char*)d_ws;
    u16* xb  = (u16*)(ws + 0);                       // 32 MiB; reused as ab after QKV GEMM
    u16* fBt = (u16*)(ws + 33554432);                // 48 MiB fused [wq^T; wk^T; wv^T]
    u16* qkv = (u16*)(ws + 83886080);                // 48 MiB [4096][6144]
    u16* vt  = (u16*)(ws + 134217728);               //  8 MiB -> total 142 MiB
    u16* ab  = xb;
    u16* wob = fBt;                                  // reuse fBt region after QKV GEMM

    float* out0 = (float*)d_out;
    float* outk = out0 + 16777216;
    float* outv = out0 + 33554432;

    convx_kernel<<<16384, 256, 0, stream>>>(x, xb);
    tconv_kernel<<<dim3(64, 64), 256, 0, stream>>>(wq, fBt, 4096, 4096);
    tconv_kernel<<<dim3(16, 64), 256, 0, stream>>>(wk, fBt + (size_t)4096 * 4096, 4096, 1024);
    tconv_kernel<<<dim3(16, 64), 256, 0, stream>>>(wv, fBt + (size_t)5120 * 4096, 4096, 1024);

    // fused QKV projection: 256x192 tiles, grid 16x32 = 512 blocks (r5 measured-best)
    gemm192_kernel<<<512, 512, 0, stream>>>(xb, fBt, qkv, 6144, 4096, 16);

    tconv_kernel<<<dim3(64, 64), 256, 0, stream>>>(wo, wob, 4096, 4096);  // fBt dead now

    rope_kernel<<<dim3(10, 4096), 256, 0, stream>>>(qkv, outk);
    vtrans_kernel<<<dim3(32, 2, 16), 256, 0, stream>>>(qkv, vt, outv);

    attn_kernel<<<dim3(16, 32, 2), 256, 0, stream>>>(qkv, vt, ab);

    // output projection: [4096 x 4096] @ [4096 x 4096] -> out0 f32 (grid 16x16 = 256, 1/CU)
    gemm256_kernel<true><<<256, 512, 0, stream>>>(ab, wob, nullptr, out0, 4096, 4096, 4096, 16);
}

// Round 9
// 591.496 us; speedup vs baseline: 1.1908x; 1.0423x over previous
//
#include <hip/hip_runtime.h>

typedef unsigned short u16;
typedef unsigned int u32;
typedef float f32x4 __attribute__((ext_vector_type(4)));
typedef u32 u32x2 __attribute__((ext_vector_type(2)));
typedef __bf16 bf16x8 __attribute__((ext_vector_type(8)));

#define DEV __device__ __forceinline__

DEV u16 f2b(float f) {
    union { float f; u32 u; } v; v.f = f;
    u32 r = v.u + 0x7fffu + ((v.u >> 16) & 1u);   // RNE
    return (u16)(r >> 16);
}
DEV float b2f(u16 b) {
    union { u32 u; float f; } v; v.u = ((u32)b) << 16;
    return v.f;
}

// global -> LDS direct (16B/lane). LDS dest must be wave-uniform base; HW adds lane*16.
DEV void gload16(const void* g, void* l) {
    __builtin_amdgcn_global_load_lds((const __attribute__((address_space(1))) void*)g,
                                     (__attribute__((address_space(3))) void*)l, 16, 0, 0);
}

DEV f32x4 mfma16(bf16x8 a, bf16x8 b, f32x4 c) {
    return __builtin_amdgcn_mfma_f32_16x16x32_bf16(a, b, c, 0, 0, 0);
}

// ---------------------------------------------------------------- convert x
__global__ __launch_bounds__(256) void convx_kernel(const float* __restrict__ in,
                                                    u16* __restrict__ out) {
    size_t i = ((size_t)blockIdx.x * 256 + threadIdx.x) * 4;
    float4 v = *(const float4*)(in + i);
    ushort4 o; o.x = f2b(v.x); o.y = f2b(v.y); o.z = f2b(v.z); o.w = f2b(v.w);
    *(ushort4*)(out + i) = o;
}

// ------------------------------------------- transpose + convert: (KxN f32) -> (NxK bf16)
__global__ __launch_bounds__(256) void tconv_kernel(const float* __restrict__ in,
                                                    u16* __restrict__ out, int K, int N) {
    __shared__ float tile[64][65];
    int t = threadIdx.x;
    int n0 = blockIdx.x * 64, k0 = blockIdx.y * 64;
    int r = t >> 4, c4 = (t & 15) * 4;
#pragma unroll
    for (int i = 0; i < 4; ++i) {
        float4 v = *(const float4*)(in + (size_t)(k0 + i * 16 + r) * N + n0 + c4);
        tile[i * 16 + r][c4 + 0] = v.x; tile[i * 16 + r][c4 + 1] = v.y;
        tile[i * 16 + r][c4 + 2] = v.z; tile[i * 16 + r][c4 + 3] = v.w;
    }
    __syncthreads();
#pragma unroll
    for (int i = 0; i < 4; ++i) {
        int nn = i * 16 + r;
        ushort4 o;
        o.x = f2b(tile[c4 + 0][nn]); o.y = f2b(tile[c4 + 1][nn]);
        o.z = f2b(tile[c4 + 2][nn]); o.w = f2b(tile[c4 + 3][nn]);
        *(ushort4*)(out + (size_t)(n0 + nn) * K + k0 + c4) = o;
    }
}

// ---------------------------------------------------------------- 256x192 4-phase GEMM (QKV)
// r5 measured-best for QKV: 242 us = 851 TF (LDS-BW-bound per r7 analysis). Unchanged.
__global__ __launch_bounds__(512, 1) void gemm192_kernel(const u16* __restrict__ A,
                                                         const u16* __restrict__ Bt,
                                                         u16* __restrict__ Cb,
                                                         int N, int K, int gy) {
    __shared__ __align__(16) u16 Asb[2][2][128 * 64];
    __shared__ __align__(16) u16 Bsb[2][192 * 64];
    int t = threadIdx.x;
    int lane = t & 63, w = t >> 6;
    int wrM = w >> 2, wcN = w & 3;
    int lr = lane & 15, hi = lane >> 4;
    int wg = blockIdx.x;
    int swz = (wg & 7) * ((int)gridDim.x >> 3) + (wg >> 3);
    int bx = swz / gy, by = swz % gy;    // column-major raster for L2 panel sharing
    int m0 = by * 256, n0 = bx * 192;
    int nk = K >> 6;

    auto stageA = [&](int X) {           // 256 rows x 64 cols, 4 passes
        const u16* src = A + (size_t)m0 * K + X * 64;
        char* dst = (char*)&Asb[X & 1][0][0];
#pragma unroll
        for (int it = 0; it < 4; ++it) {
            int c = it * 512 + t;
            int row = c >> 3;
            int col8 = ((c & 7) ^ (row & 7)) << 3;
            gload16(src + (size_t)row * K + col8, dst + (it * 512 + (t & ~63)) * 16);
        }
    };
    auto stageB = [&](int X) {           // 192 rows x 64 cols, 3 passes
        const u16* src = Bt + (size_t)n0 * K + X * 64;
        char* dst = (char*)&Bsb[X & 1][0];
#pragma unroll
        for (int it = 0; it < 3; ++it) {
            int c = it * 512 + t;
            int row = c >> 3;
            int col8 = ((c & 7) ^ (row & 7)) << 3;
            gload16(src + (size_t)row * K + col8, dst + (it * 512 + (t & ~63)) * 16);
        }
    };

    stageA(0); stageB(0); stageA(1); stageB(1);
    asm volatile("s_waitcnt vmcnt(7)" ::: "memory");   // tile0 landed
    __builtin_amdgcn_s_barrier();

    f32x4 acc[8][3] = {};
    for (int kt = 0; kt < nk; ++kt) {
        __builtin_amdgcn_sched_barrier(0);
        int p = kt & 1;
        const char* Ah = (const char*)&Asb[p][wrM][0];
        const char* Bh = (const char*)&Bsb[p][0];
        bool s1 = (kt + 1 < nk), s2 = (kt + 2 < nk);
        bf16x8 a[8][2], bb[2][2], bc[2];

        // ---- ph0
#pragma unroll
        for (int mf = 0; mf < 4; ++mf)
#pragma unroll
            for (int ks = 0; ks < 2; ++ks) {
                int row = mf * 16 + lr;
                a[mf][ks] = *(const bf16x8*)(Ah + ((row * 128 + ks * 64 + hi * 16) ^ ((row & 7) << 4)));
            }
#pragma unroll
        for (int nf = 0; nf < 2; ++nf)
#pragma unroll
            for (int ks = 0; ks < 2; ++ks) {
                int row = wcN * 48 + nf * 16 + lr;
                bb[nf][ks] = *(const bf16x8*)(Bh + ((row * 128 + ks * 64 + hi * 16) ^ ((row & 7) << 4)));
            }
        __builtin_amdgcn_s_barrier();
        __builtin_amdgcn_s_setprio(1);
#pragma unroll
        for (int mf = 0; mf < 4; ++mf)
#pragma unroll
            for (int nf = 0; nf < 2; ++nf)
#pragma unroll
                for (int ks = 0; ks < 2; ++ks)
                    acc[mf][nf] = mfma16(a[mf][ks], bb[nf][ks], acc[mf][nf]);
        __builtin_amdgcn_s_setprio(0);
        __builtin_amdgcn_s_barrier();

        // ---- ph1
#pragma unroll
        for (int mf = 4; mf < 8; ++mf)
#pragma unroll
            for (int ks = 0; ks < 2; ++ks) {
                int row = mf * 16 + lr;
                a[mf][ks] = *(const bf16x8*)(Ah + ((row * 128 + ks * 64 + hi * 16) ^ ((row & 7) << 4)));
            }
        __builtin_amdgcn_s_barrier();
        __builtin_amdgcn_s_setprio(1);
#pragma unroll
        for (int mf = 4; mf < 8; ++mf)
#pragma unroll
            for (int nf = 0; nf < 2; ++nf)
#pragma unroll
                for (int ks = 0; ks < 2; ++ks)
                    acc[mf][nf] = mfma16(a[mf][ks], bb[nf][ks], acc[mf][nf]);
        __builtin_amdgcn_s_setprio(0);
        __builtin_amdgcn_s_barrier();

        // ---- ph2: stage A(kt+2)
#pragma unroll
        for (int ks = 0; ks < 2; ++ks) {
            int row = wcN * 48 + 32 + lr;
            bc[ks] = *(const bf16x8*)(Bh + ((row * 128 + ks * 64 + hi * 16) ^ ((row & 7) << 4)));
        }
        if (s2) stageA(kt + 2);
        __builtin_amdgcn_s_barrier();
        __builtin_amdgcn_s_setprio(1);
#pragma unroll
        for (int mf = 4; mf < 8; ++mf)
#pragma unroll
            for (int ks = 0; ks < 2; ++ks)
                acc[mf][2] = mfma16(a[mf][ks], bc[ks], acc[mf][2]);
        __builtin_amdgcn_s_setprio(0);
        __builtin_amdgcn_s_barrier();

        // ---- ph3: stage B(kt+2); boundary vmcnt
        if (s2) stageB(kt + 2);
        __builtin_amdgcn_s_barrier();
        __builtin_amdgcn_s_setprio(1);
#pragma unroll
        for (int mf = 0; mf < 4; ++mf)
#pragma unroll
            for (int ks = 0; ks < 2; ++ks)
                acc[mf][2] = mfma16(a[mf][ks], bc[ks], acc[mf][2]);
        __builtin_amdgcn_s_setprio(0);
        if (s1) {
            if (s2) asm volatile("s_waitcnt vmcnt(7)" ::: "memory");
            else    asm volatile("s_waitcnt vmcnt(0)" ::: "memory");
        }
        __builtin_amdgcn_s_barrier();
    }

#pragma unroll
    for (int mf = 0; mf < 8; ++mf)
#pragma unroll
        for (int nf = 0; nf < 3; ++nf)
#pragma unroll
            for (int r = 0; r < 4; ++r) {
                int m = m0 + wrM * 128 + mf * 16 + hi * 4 + r;
                int n = n0 + wcN * 48 + nf * 16 + lr;
                Cb[(size_t)m * N + n] = f2b(acc[mf][nf][r]);
            }
}

// ---------------------------------------------------------------- 256x256 8-phase GEMM (WO)
template <bool F32OUT>
__global__ __launch_bounds__(512, 1) void gemm256_kernel(const u16* __restrict__ A,
                                                         const u16* __restrict__ Bt,
                                                         u16* __restrict__ Cb,
                                                         float* __restrict__ Cf,
                                                         int M, int N, int K, int gy) {
    __shared__ __align__(16) u16 Asb[2][2][128 * 64];
    __shared__ __align__(16) u16 Bsb[2][2][128 * 64];
    (void)M;
    int t = threadIdx.x;
    int lane = t & 63, w = t >> 6;
    int wrM = w >> 2, wcN = w & 3;
    int lr = lane & 15, hi = lane >> 4;
    int wg = blockIdx.x;
    int swz = (wg & 7) * ((int)gridDim.x >> 3) + (wg >> 3);
    int bx = swz / gy, by = swz % gy;
    int m0 = by * 256, n0 = bx * 256;
    int nk = K >> 6;

    auto stageA = [&](int X, int h) {
        const u16* src = A + (size_t)(m0 + h * 128) * K + X * 64;
        char* dst = (char*)&Asb[X & 1][h][0];
#pragma unroll
        for (int it = 0; it < 2; ++it) {
            int c = it * 512 + t;
            int row = c >> 3;
            int col8 = ((c & 7) ^ (row & 7)) << 3;
            gload16(src + (size_t)row * K + col8, dst + (it * 512 + (t & ~63)) * 16);
        }
    };
    auto stageB = [&](int X, int h) {
        const u16* src = Bt + (size_t)(n0 + h * 128) * K + X * 64;
        char* dst = (char*)&Bsb[X & 1][h][0];
#pragma unroll
        for (int it = 0; it < 2; ++it) {
            int c = it * 512 + t;
            int row = c >> 3;
            int col8 = ((c & 7) ^ (row & 7)) << 3;
            gload16(src + (size_t)row * K + col8, dst + (it * 512 + (t & ~63)) * 16);
        }
    };

    stageA(0, 0); stageA(0, 1); stageB(0, 0); stageB(0, 1);
    stageA(1, 0); stageA(1, 1); stageB(1, 0);
    asm volatile("s_waitcnt vmcnt(6)" ::: "memory");
    __builtin_amdgcn_s_barrier();

    f32x4 acc[8][4] = {};
    for (int kt = 0; kt < nk; ++kt) {
        __builtin_amdgcn_sched_barrier(0);
        int p = kt & 1;
        const char* Ah = (const char*)&Asb[p][wrM][0];
        const char* Bh = (const char*)&Bsb[p][wcN >> 1][0];
        bool s1 = (kt + 1 < nk), s2 = (kt + 2 < nk);
        bf16x8 a[8][2], bb[2][2];

        // ---- ph0
#pragma unroll
        for (int mf = 0; mf < 4; ++mf)
#pragma unroll
            for (int ks = 0; ks < 2; ++ks) {
                int row = mf * 16 + lr;
                a[mf][ks] = *(const bf16x8*)(Ah + ((row * 128 + ks * 64 + hi * 16) ^ ((row & 7) << 4)));
            }
#pragma unroll
        for (int nf = 0; nf < 2; ++nf)
#pragma unroll
            for (int ks = 0; ks < 2; ++ks) {
                int row = (wcN & 1) * 64 + nf * 16 + lr;
                bb[nf][ks] = *(const bf16x8*)(Bh + ((row * 128 + ks * 64 + hi * 16) ^ ((row & 7) << 4)));
            }
        if (s1) stageB(kt + 1, 1);
        __builtin_amdgcn_s_barrier();
        __builtin_amdgcn_s_setprio(1);
#pragma unroll
        for (int mf = 0; mf < 4; ++mf)
#pragma unroll
            for (int nf = 0; nf < 2; ++nf)
#pragma unroll
                for (int ks = 0; ks < 2; ++ks)
                    acc[mf][nf] = mfma16(a[mf][ks], bb[nf][ks], acc[mf][nf]);
        __builtin_amdgcn_s_setprio(0);
        __builtin_amdgcn_s_barrier();

        // ---- ph1
#pragma unroll
        for (int mf = 4; mf < 8; ++mf)
#pragma unroll
            for (int ks = 0; ks < 2; ++ks) {
                int row = mf * 16 + lr;
                a[mf][ks] = *(const bf16x8*)(Ah + ((row * 128 + ks * 64 + hi * 16) ^ ((row & 7) << 4)));
            }
        __builtin_amdgcn_s_barrier();
        __builtin_amdgcn_s_setprio(1);
#pragma unroll
        for (int mf = 4; mf < 8; ++mf)
#pragma unroll
            for (int nf = 0; nf < 2; ++nf)
#pragma unroll
                for (int ks = 0; ks < 2; ++ks)
                    acc[mf][nf] = mfma16(a[mf][ks], bb[nf][ks], acc[mf][nf]);
        __builtin_amdgcn_s_setprio(0);
        __builtin_amdgcn_s_barrier();

        // ---- ph2
#pragma unroll
        for (int nf = 0; nf < 2; ++nf)
#pragma unroll
            for (int ks = 0; ks < 2; ++ks) {
                int row = (wcN & 1) * 64 + (nf + 2) * 16 + lr;
                bb[nf][ks] = *(const bf16x8*)(Bh + ((row * 128 + ks * 64 + hi * 16) ^ ((row & 7) << 4)));
            }
        if (s2) { stageA(kt + 2, 0); stageA(kt + 2, 1); }
        __builtin_amdgcn_s_barrier();
        __builtin_amdgcn_s_setprio(1);
#pragma unroll
        for (int mf = 4; mf < 8; ++mf)
#pragma unroll
            for (int nf = 0; nf < 2; ++nf)
#pragma unroll
                for (int ks = 0; ks < 2; ++ks)
                    acc[mf][nf + 2] = mfma16(a[mf][ks], bb[nf][ks], acc[mf][nf + 2]);
        __builtin_amdgcn_s_setprio(0);
        __builtin_amdgcn_s_barrier();

        // ---- ph3
        if (s2) stageB(kt + 2, 0);
        __builtin_amdgcn_s_barrier();
        __builtin_amdgcn_s_setprio(1);
#pragma unroll
        for (int mf = 0; mf < 4; ++mf)
#pragma unroll
            for (int nf = 0; nf < 2; ++nf)
#pragma unroll
                for (int ks = 0; ks < 2; ++ks)
                    acc[mf][nf + 2] = mfma16(a[mf][ks], bb[nf][ks], acc[mf][nf + 2]);
        __builtin_amdgcn_s_setprio(0);
        if (s1) {
            if (s2) asm volatile("s_waitcnt vmcnt(6)" ::: "memory");
            else    asm volatile("s_waitcnt vmcnt(0)" ::: "memory");
        }
        __builtin_amdgcn_s_barrier();
    }

#pragma unroll
    for (int mf = 0; mf < 8; ++mf)
#pragma unroll
        for (int nf = 0; nf < 4; ++nf)
#pragma unroll
            for (int r = 0; r < 4; ++r) {
                int m = m0 + wrM * 128 + mf * 16 + hi * 4 + r;
                int n = n0 + wcN * 64 + nf * 16 + lr;
                if (F32OUT) Cf[(size_t)m * N + n] = acc[mf][nf][r];
                else        Cb[(size_t)m * N + n] = f2b(acc[mf][nf][r]);
            }
}

// ------------------------------- RoPE in-place on fused qkv (stride 6144) + roped-k f32 out
__global__ __launch_bounds__(256) void rope_kernel(u16* __restrict__ qkv,
                                                   float* __restrict__ outk) {
    int row = blockIdx.y;                    // b*2048 + l
    int p = blockIdx.x * 256 + threadIdx.x;  // 0..2559: 32 q-heads + 8 kv-heads, 64 pairs each
    int b = row >> 11, l = row & 2047;
    float freq = exp2f((float)(p & 63) * -0.2076205059304601f);  // 10000^(-i/64)
    float sv, cv; sincosf((float)l * freq, &sv, &cv);
    if (p < 2048) {
        int h = p >> 6, i = p & 63;
        size_t idx = (size_t)row * 6144 + h * 128 + 2 * i;
        u32 pr = *(const u32*)(qkv + idx);
        float x1 = b2f((u16)(pr & 0xffff)), x2 = b2f((u16)(pr >> 16));
        float o1 = x1 * cv + x2 * sv, o2 = x1 * sv - x2 * cv;
        *(u32*)(qkv + idx) = (u32)f2b(o1) | ((u32)f2b(o2) << 16);
    } else {
        int kvh = (p >> 6) - 32, i = p & 63;
        size_t idx = (size_t)row * 6144 + 4096 + kvh * 128 + 2 * i;
        u32 pr = *(const u32*)(qkv + idx);
        float x1 = b2f((u16)(pr & 0xffff)), x2 = b2f((u16)(pr >> 16));
        float o1 = x1 * cv + x2 * sv, o2 = x1 * sv - x2 * cv;
        *(u32*)(qkv + idx) = (u32)f2b(o1) | ((u32)f2b(o2) << 16);
#pragma unroll
        for (int r = 0; r < 4; ++r) {
            float2 o; o.x = o1; o.y = o2;
            *(float2*)(outk + ((size_t)((b * 32 + kvh * 4 + r) * 2048) + l) * 128 + 2 * i) = o;
        }
    }
}

// --------------------------------- V: write f32 x4 GQA copies to d_out + bf16 V^T for attention
__global__ __launch_bounds__(256) void vtrans_kernel(const u16* __restrict__ qkv,
                                                     u16* __restrict__ vt,
                                                     float* __restrict__ outv) {
    __shared__ u16 tile[64][65];
    int t = threadIdx.x;
    int l0 = blockIdx.x * 64, d0 = blockIdx.y * 64;
    int z = blockIdx.z, b = z >> 3, kvh = z & 7;
    int r = t >> 4, c4 = (t & 15) * 4;
#pragma unroll
    for (int i = 0; i < 4; ++i) {
        int l = l0 + i * 16 + r;
        ushort4 v = *(const ushort4*)(qkv + (size_t)(b * 2048 + l) * 6144 + 5120 + kvh * 128 + d0 + c4);
        tile[i * 16 + r][c4 + 0] = v.x; tile[i * 16 + r][c4 + 1] = v.y;
        tile[i * 16 + r][c4 + 2] = v.z; tile[i * 16 + r][c4 + 3] = v.w;
        float4 f; f.x = b2f(v.x); f.y = b2f(v.y); f.z = b2f(v.z); f.w = b2f(v.w);
#pragma unroll
        for (int rr = 0; rr < 4; ++rr)
            *(float4*)(outv + ((size_t)((b * 32 + kvh * 4 + rr) * 2048) + l) * 128 + d0 + c4) = f;
    }
    __syncthreads();
#pragma unroll
    for (int i = 0; i < 4; ++i) {
        int dn = i * 16 + r;
        ushort4 o;
        o.x = tile[c4 + 0][dn]; o.y = tile[c4 + 1][dn];
        o.z = tile[c4 + 2][dn]; o.w = tile[c4 + 3][dn];
        *(ushort4*)(vt + (size_t)((b * 8 + kvh) * 128 + d0 + dn) * 2048 + l0 + c4) = o;
    }
}

// ---------------------------------------------------------------- flash attention v4.1
// 32 q-rows per wave (two 16-row halves sharing every K/V fragment read): QBLK=128/block,
// grid (8,32,2) = 512 blocks = exactly 2/CU (LDS 80 KB). r8 bug fixed: per-wave P is
// [q=32][kv=64] bf16 = 128 B/row, so the half-1 row block starts at 16*128 = 2048 B
// (r8 wrongly used 4096 -> cross-wave LDS corruption).
__global__ __launch_bounds__(256, 2) void attn_kernel(const u16* __restrict__ qkv,
                                                      const u16* __restrict__ vt,
                                                      u16* __restrict__ ab) {
    __shared__ __align__(16) u16 Kbuf[2][64 * 128];   // K tile [kv][dh]     32 KB
    __shared__ __align__(16) u16 Vbuf[2][128 * 64];   // V^T tile [dh][kv]   32 KB
    __shared__ __align__(16) u16 Ps[4][32 * 64];      // per-wave P [q=32][kv=64]  16 KB
    int t = threadIdx.x, lane = t & 63, w = t >> 6;
    int lr = lane & 15, hi = lane >> 4;
    int h = blockIdx.y, b = blockIdx.z, kvh = h >> 2;

    const u16* kbase = qkv + (size_t)(b * 2048) * 6144 + 4096 + kvh * 128;
    const u16* vtbase = vt + (size_t)((b * 8 + kvh) * 128) * 2048;

    auto stageKV = [&](int k0, int buf) {
#pragma unroll
        for (int i = 0; i < 4; ++i) {   // K: 64 rows x 128 cols
            int c = i * 256 + t;
            int row = c >> 4;
            int col8 = ((c & 15) ^ (row & 7)) << 3;
            gload16(kbase + (size_t)(k0 + row) * 6144 + col8,
                    (char*)Kbuf[buf] + (i * 256 + (t & ~63)) * 16);
        }
#pragma unroll
        for (int i = 0; i < 4; ++i) {   // V^T: 128 rows x 64 cols
            int c = i * 256 + t;
            int row = c >> 3;
            int col8 = ((c & 7) ^ (row & 7)) << 3;
            gload16(vtbase + (size_t)row * 2048 + k0 + col8,
                    (char*)Vbuf[buf] + (i * 256 + (t & ~63)) * 16);
        }
    };

    auto process = [&](int qblk) {
        int q0 = qblk * 128;
        // this lane's two q-rows: q0 + w*32 + half*16 + lr
        bf16x8 qf[2][4];
#pragma unroll
        for (int half = 0; half < 2; ++half)
#pragma unroll
            for (int kki = 0; kki < 4; ++kki)
                qf[half][kki] = *(const bf16x8*)(qkv +
                    (size_t)(b * 2048 + q0 + w * 32 + half * 16 + lr) * 6144 + h * 128 +
                    kki * 32 + 8 * hi);
        f32x4 acc[2][8] = {};
        float mrun[2] = {-1e30f, -1e30f}, lrun[2] = {0.f, 0.f};

        int nt = 2 * (qblk + 1);
        stageKV(0, 0);
        __syncthreads();
        int cur = 0;
        for (int kt = 0; kt < nt; ++kt) {
            if (kt + 1 < nt) stageKV((kt + 1) * 64, cur ^ 1);  // prefetch next tile
            __builtin_amdgcn_sched_barrier(0);

            const u16* Ks = Kbuf[cur];
            const u16* Vs = Vbuf[cur];
            // S^T = K Q^T for both halves, sharing each kf read
            f32x4 s[2][4] = {};
            __builtin_amdgcn_s_setprio(1);
#pragma unroll
            for (int kki = 0; kki < 4; ++kki) {
                bf16x8 kf[4];
#pragma unroll
                for (int fc = 0; fc < 4; ++fc) {
                    int kvr = fc * 16 + lr;
                    int byt = (kvr * 256 + (kki * 32 + 8 * hi) * 2) ^ ((kvr & 7) << 4);
                    kf[fc] = *(const bf16x8*)((const char*)Ks + byt);
                }
#pragma unroll
                for (int fc = 0; fc < 4; ++fc) {
                    s[0][fc] = mfma16(kf[fc], qf[0][kki], s[0][fc]);
                    s[1][fc] = mfma16(kf[fc], qf[1][kki], s[1][fc]);
                }
            }
            __builtin_amdgcn_s_setprio(0);
            const float SC = 0.08838834764831845f;  // 1/sqrt(128)
            int domask = (kt >= nt - 2);
            u16* Pw = Ps[w];
#pragma unroll
            for (int half = 0; half < 2; ++half) {
                int qabs = q0 + w * 32 + half * 16 + lr;
#pragma unroll
                for (int fc = 0; fc < 4; ++fc)
#pragma unroll
                    for (int r = 0; r < 4; ++r) {
                        float v = s[half][fc][r] * SC;
                        if (domask && (kt * 64 + fc * 16 + hi * 4 + r) > qabs) v = -1e30f;
                        s[half][fc][r] = v;
                    }
                // online softmax, scalar per lane (one q-row per half)
                float pm = s[half][0][0];
#pragma unroll
                for (int fc = 0; fc < 4; ++fc)
#pragma unroll
                    for (int r = 0; r < 4; ++r) pm = fmaxf(pm, s[half][fc][r]);
                pm = fmaxf(pm, __shfl_xor(pm, 16));
                pm = fmaxf(pm, __shfl_xor(pm, 32));
                float mn = fmaxf(mrun[half], pm);
                float fr = __expf(mrun[half] - mn);
                mrun[half] = mn;
                float ls = 0.f;
#pragma unroll
                for (int fc = 0; fc < 4; ++fc)
#pragma unroll
                    for (int r = 0; r < 4; ++r) {
                        float e = __expf(s[half][fc][r] - mn);
                        s[half][fc][r] = e;
                        ls += e;
                    }
                ls += __shfl_xor(ls, 16);
                ls += __shfl_xor(ls, 32);
                lrun[half] = lrun[half] * fr + ls;
#pragma unroll
                for (int dhf = 0; dhf < 8; ++dhf)
#pragma unroll
                    for (int r = 0; r < 4; ++r) acc[half][dhf][r] *= fr;
                // P -> LDS: row q = half*16+lr (128 B/row -> half block at 2048 B)
#pragma unroll
                for (int fc = 0; fc < 4; ++fc) {
                    u32x2 pk;
                    pk.x = (u32)f2b(s[half][fc][0]) | ((u32)f2b(s[half][fc][1]) << 16);
                    pk.y = (u32)f2b(s[half][fc][2]) | ((u32)f2b(s[half][fc][3]) << 16);
                    int byt = (half * 2048 + lr * 128 + fc * 32 + hi * 8) ^ ((lr & 7) << 4);
                    *(u32x2*)((char*)Pw + byt) = pk;
                }
            }
            asm volatile("s_waitcnt lgkmcnt(0)" ::: "memory");
            // O^T += V^T P^T; each vf read shared by both halves
            __builtin_amdgcn_s_setprio(1);
#pragma unroll
            for (int kk2 = 0; kk2 < 2; ++kk2) {
                bf16x8 pf0 = *(const bf16x8*)((const char*)Pw +
                    ((lr * 128 + kk2 * 64 + hi * 16) ^ ((lr & 7) << 4)));
                bf16x8 pf1 = *(const bf16x8*)((const char*)Pw +
                    ((2048 + lr * 128 + kk2 * 64 + hi * 16) ^ ((lr & 7) << 4)));
#pragma unroll
                for (int dhf = 0; dhf < 8; ++dhf) {
                    int dh = dhf * 16 + lr;
                    int bytv = (dh * 128 + (kk2 * 32 + 8 * hi) * 2) ^ ((dh & 7) << 4);
                    bf16x8 vf = *(const bf16x8*)((const char*)Vs + bytv);
                    acc[0][dhf] = mfma16(vf, pf0, acc[0][dhf]);
                    acc[1][dhf] = mfma16(vf, pf1, acc[1][dhf]);
                }
            }
            __builtin_amdgcn_s_setprio(0);
            __syncthreads();   // drains vmcnt -> prefetched tile ready; buf[cur] reads retired
            cur ^= 1;
        }
        // epilogue: acc[half][dhf][r] = O[dh=dhf*16+hi*4+r][q]; pack 4 dh per store
#pragma unroll
        for (int half = 0; half < 2; ++half) {
            float inv = 1.0f / lrun[half];
            int qrow = q0 + w * 32 + half * 16 + lr;
#pragma unroll
            for (int dhf = 0; dhf < 8; ++dhf) {
                ushort4 o;
                o.x = f2b(acc[half][dhf][0] * inv); o.y = f2b(acc[half][dhf][1] * inv);
                o.z = f2b(acc[half][dhf][2] * inv); o.w = f2b(acc[half][dhf][3] * inv);
                *(ushort4*)(ab + (size_t)(b * 2048 + qrow) * 4096 + h * 128 + dhf * 16 + hi * 4) = o;
            }
        }
    };

    process(15 - blockIdx.x);   // long tile first
    __syncthreads();
    process(blockIdx.x);
}

// ---------------------------------------------------------------- launch
extern "C" void kernel_launch(void* const* d_in, const int* in_sizes, int n_in,
                              void* d_out, int out_size, void* d_ws, size_t ws_size,
                              hipStream_t stream) {
    (void)in_sizes; (void)n_in; (void)out_size; (void)ws_size;
    const float* x  = (const float*)d_in[0];
    // d_in[1] = mask: exact causal tril(0 / -1e9) — handled analytically in attn_kernel
    const float* wq = (const float*)d_in[2];
    const float* wk = (const float*)d_in[3];
    const float* wv = (const float*)d_in[4];
    const float* wo = (const float*)d_in[5];

    char* ws = (char*)d_ws;
    u16* xb  = (u16*)(ws + 0);                       // 32 MiB; reused as ab after QKV GEMM
    u16* fBt = (u16*)(ws + 33554432);                // 48 MiB fused [wq^T; wk^T; wv^T]
    u16* qkv = (u16*)(ws + 83886080);                // 48 MiB [4096][6144]
    u16* vt  = (u16*)(ws + 134217728);               //  8 MiB -> total 142 MiB
    u16* ab  = xb;
    u16* wob = fBt;                                  // reuse fBt region after QKV GEMM

    float* out0 = (float*)d_out;
    float* outk = out0 + 16777216;
    float* outv = out0 + 33554432;

    convx_kernel<<<16384, 256, 0, stream>>>(x, xb);
    tconv_kernel<<<dim3(64, 64), 256, 0, stream>>>(wq, fBt, 4096, 4096);
    tconv_kernel<<<dim3(16, 64), 256, 0, stream>>>(wk, fBt + (size_t)4096 * 4096, 4096, 1024);
    tconv_kernel<<<dim3(16, 64), 256, 0, stream>>>(wv, fBt + (size_t)5120 * 4096, 4096, 1024);

    // fused QKV projection: 256x192 tiles, grid 16x32 = 512 blocks (r5 measured-best)
    gemm192_kernel<<<512, 512, 0, stream>>>(xb, fBt, qkv, 6144, 4096, 16);

    tconv_kernel<<<dim3(64, 64), 256, 0, stream>>>(wo, wob, 4096, 4096);  // fBt dead now

    rope_kernel<<<dim3(10, 4096), 256, 0, stream>>>(qkv, outk);
    vtrans_kernel<<<dim3(32, 2, 16), 256, 0, stream>>>(qkv, vt, outv);

    attn_kernel<<<dim3(8, 32, 2), 256, 0, stream>>>(qkv, vt, ab);

    // output projection: [4096 x 4096] @ [4096 x 4096] -> out0 f32 (grid 16x16 = 256, 1/CU)
    gemm256_kernel<true><<<256, 512, 0, stream>>>(ab, wob, nullptr, out0, 4096, 4096, 4096, 16);
}

// Round 10
// 580.951 us; speedup vs baseline: 1.2124x; 1.0181x over previous
//
#include <hip/hip_runtime.h>

typedef unsigned short u16;
typedef unsigned int u32;
typedef float f32x4 __attribute__((ext_vector_type(4)));
typedef u32 u32x2 __attribute__((ext_vector_type(2)));
typedef __bf16 bf16x8 __attribute__((ext_vector_type(8)));

#define DEV __device__ __forceinline__

DEV u16 f2b(float f) {
    union { float f; u32 u; } v; v.f = f;
    u32 r = v.u + 0x7fffu + ((v.u >> 16) & 1u);   // RNE
    return (u16)(r >> 16);
}
DEV float b2f(u16 b) {
    union { u32 u; float f; } v; v.u = ((u32)b) << 16;
    return v.f;
}

// global -> LDS direct (16B/lane). LDS dest must be wave-uniform base; HW adds lane*16.
DEV void gload16(const void* g, void* l) {
    __builtin_amdgcn_global_load_lds((const __attribute__((address_space(1))) void*)g,
                                     (__attribute__((address_space(3))) void*)l, 16, 0, 0);
}

DEV f32x4 mfma16(bf16x8 a, bf16x8 b, f32x4 c) {
    return __builtin_amdgcn_mfma_f32_16x16x32_bf16(a, b, c, 0, 0, 0);
}

// ---------------------------------------------------------------- convert x
__global__ __launch_bounds__(256) void convx_kernel(const float* __restrict__ in,
                                                    u16* __restrict__ out) {
    size_t i = ((size_t)blockIdx.x * 256 + threadIdx.x) * 4;
    float4 v = *(const float4*)(in + i);
    ushort4 o; o.x = f2b(v.x); o.y = f2b(v.y); o.z = f2b(v.z); o.w = f2b(v.w);
    *(ushort4*)(out + i) = o;
}

// ------------------------------------------- transpose + convert: (KxN f32) -> (NxK bf16)
__global__ __launch_bounds__(256) void tconv_kernel(const float* __restrict__ in,
                                                    u16* __restrict__ out, int K, int N) {
    __shared__ float tile[64][65];
    int t = threadIdx.x;
    int n0 = blockIdx.x * 64, k0 = blockIdx.y * 64;
    int r = t >> 4, c4 = (t & 15) * 4;
#pragma unroll
    for (int i = 0; i < 4; ++i) {
        float4 v = *(const float4*)(in + (size_t)(k0 + i * 16 + r) * N + n0 + c4);
        tile[i * 16 + r][c4 + 0] = v.x; tile[i * 16 + r][c4 + 1] = v.y;
        tile[i * 16 + r][c4 + 2] = v.z; tile[i * 16 + r][c4 + 3] = v.w;
    }
    __syncthreads();
#pragma unroll
    for (int i = 0; i < 4; ++i) {
        int nn = i * 16 + r;
        ushort4 o;
        o.x = f2b(tile[c4 + 0][nn]); o.y = f2b(tile[c4 + 1][nn]);
        o.z = f2b(tile[c4 + 2][nn]); o.w = f2b(tile[c4 + 3][nn]);
        *(ushort4*)(out + (size_t)(n0 + nn) * K + k0 + c4) = o;
    }
}

// ---------------------------------------------------------------- 128x128 2-phase GEMM
// Occupancy experiment (r10): 4 waves (2x2), LDS 64 KiB -> 2 INDEPENDENT blocks/CU
// (launch_bounds(256,2)). Same wave count per CU as the 256-tile versions (8) but split
// across two barrier-independent blocks, so one block's MFMA covers the other's
// vmcnt/barrier stalls (r9 theory: synchronized single-block stall = the 35% cap).
// Per K-tile, 2 phases: ph0 {read a0-3,b0-1; stage B(kt+1) -> Bsb[1-p]; MFMA nf0-1},
// ph1 {read b2-3; stage A(kt+2) -> Asb[p]; MFMA nf2-3; boundary vmcnt(4)}.
// Race-freedom: Bsb[1-p] last read at kt-1 ph1 (registers) -> staged kt ph0 after the
// intervening barriers; Asb[p] A-reads complete by ph0's closing barrier -> staged ph1.
// Boundary vmcnt(4): the 4 newest outstanding = A(kt+2); everything of kt+1 landed.
template <bool F32OUT>
__global__ __launch_bounds__(256, 2) void gemm128_kernel(const u16* __restrict__ A,
                                                         const u16* __restrict__ Bt,
                                                         u16* __restrict__ Cb,
                                                         float* __restrict__ Cf,
                                                         int N, int K, int gy) {
    __shared__ __align__(16) u16 Asb[2][2][64 * 64];   // [dbuf][half][64r][64c]
    __shared__ __align__(16) u16 Bsb[2][2][64 * 64];
    int t = threadIdx.x;
    int lane = t & 63, w = t >> 6;
    int wrM = w >> 1, wcN = w & 1;
    int lr = lane & 15, hi = lane >> 4;
    int wg = blockIdx.x;
    int swz = (wg & 7) * ((int)gridDim.x >> 3) + (wg >> 3);
    int bx = swz / gy, by = swz % gy;    // column-major raster: L2 panel sharing
    int m0 = by * 128, n0 = bx * 128;
    int nk = K >> 6;

    auto stageA = [&](int X, int h) {    // 64 rows x 64 cols, 2 passes of 256x16B
        const u16* src = A + (size_t)(m0 + h * 64) * K + X * 64;
        char* dst = (char*)&Asb[X & 1][h][0];
#pragma unroll
        for (int it = 0; it < 2; ++it) {
            int c = it * 256 + t;
            int row = c >> 3;
            int col8 = ((c & 7) ^ (row & 7)) << 3;
            gload16(src + (size_t)row * K + col8, dst + (it * 256 + (t & ~63)) * 16);
        }
    };
    auto stageB = [&](int X, int h) {
        const u16* src = Bt + (size_t)(n0 + h * 64) * K + X * 64;
        char* dst = (char*)&Bsb[X & 1][h][0];
#pragma unroll
        for (int it = 0; it < 2; ++it) {
            int c = it * 256 + t;
            int row = c >> 3;
            int col8 = ((c & 7) ^ (row & 7)) << 3;
            gload16(src + (size_t)row * K + col8, dst + (it * 256 + (t & ~63)) * 16);
        }
    };

    // prologue: tile0 complete (8 passes) + A(1) (4 passes); vmcnt(4) -> tile0 landed
    stageA(0, 0); stageA(0, 1); stageB(0, 0); stageB(0, 1);
    stageA(1, 0); stageA(1, 1);
    asm volatile("s_waitcnt vmcnt(4)" ::: "memory");
    __builtin_amdgcn_s_barrier();

    f32x4 acc[4][4] = {};
    for (int kt = 0; kt < nk; ++kt) {
        __builtin_amdgcn_sched_barrier(0);
        int p = kt & 1;
        const char* Ah = (const char*)&Asb[p][wrM][0];
        const char* Bh = (const char*)&Bsb[p][wcN][0];
        bool s1 = (kt + 1 < nk), s2 = (kt + 2 < nk);
        bf16x8 a[4][2], bb[2][2];

        // ---- ph0: read a0-3 + b0-1; stage B(kt+1); MFMA nf0-1
#pragma unroll
        for (int mf = 0; mf < 4; ++mf)
#pragma unroll
            for (int ks = 0; ks < 2; ++ks) {
                int row = mf * 16 + lr;
                a[mf][ks] = *(const bf16x8*)(Ah + ((row * 128 + ks * 64 + hi * 16) ^ ((row & 7) << 4)));
            }
#pragma unroll
        for (int nf = 0; nf < 2; ++nf)
#pragma unroll
            for (int ks = 0; ks < 2; ++ks) {
                int row = nf * 16 + lr;
                bb[nf][ks] = *(const bf16x8*)(Bh + ((row * 128 + ks * 64 + hi * 16) ^ ((row & 7) << 4)));
            }
        if (s1) { stageB(kt + 1, 0); stageB(kt + 1, 1); }
        __builtin_amdgcn_s_barrier();
        __builtin_amdgcn_s_setprio(1);
#pragma unroll
        for (int mf = 0; mf < 4; ++mf)
#pragma unroll
            for (int nf = 0; nf < 2; ++nf)
#pragma unroll
                for (int ks = 0; ks < 2; ++ks)
                    acc[mf][nf] = mfma16(a[mf][ks], bb[nf][ks], acc[mf][nf]);
        __builtin_amdgcn_s_setprio(0);
        __builtin_amdgcn_s_barrier();

        // ---- ph1: read b2-3; stage A(kt+2); MFMA nf2-3; boundary vmcnt
#pragma unroll
        for (int nf = 0; nf < 2; ++nf)
#pragma unroll
            for (int ks = 0; ks < 2; ++ks) {
                int row = (nf + 2) * 16 + lr;
                bb[nf][ks] = *(const bf16x8*)(Bh + ((row * 128 + ks * 64 + hi * 16) ^ ((row & 7) << 4)));
            }
        if (s2) { stageA(kt + 2, 0); stageA(kt + 2, 1); }
        __builtin_amdgcn_s_barrier();
        __builtin_amdgcn_s_setprio(1);
#pragma unroll
        for (int mf = 0; mf < 4; ++mf)
#pragma unroll
            for (int nf = 0; nf < 2; ++nf)
#pragma unroll
                for (int ks = 0; ks < 2; ++ks)
                    acc[mf][nf + 2] = mfma16(a[mf][ks], bb[nf][ks], acc[mf][nf + 2]);
        __builtin_amdgcn_s_setprio(0);
        if (s2)      asm volatile("s_waitcnt vmcnt(4)" ::: "memory");  // kt+1 fully landed
        else if (s1) asm volatile("s_waitcnt vmcnt(0)" ::: "memory");  // tail: drain
        __builtin_amdgcn_s_barrier();
    }

    // epilogue
#pragma unroll
    for (int mf = 0; mf < 4; ++mf)
#pragma unroll
        for (int nf = 0; nf < 4; ++nf)
#pragma unroll
            for (int r = 0; r < 4; ++r) {
                int m = m0 + wrM * 64 + mf * 16 + hi * 4 + r;
                int n = n0 + wcN * 64 + nf * 16 + lr;
                if (F32OUT) Cf[(size_t)m * N + n] = acc[mf][nf][r];
                else        Cb[(size_t)m * N + n] = f2b(acc[mf][nf][r]);
            }
}

// ------------------------------- RoPE in-place on fused qkv (stride 6144) + roped-k f32 out
__global__ __launch_bounds__(256) void rope_kernel(u16* __restrict__ qkv,
                                                   float* __restrict__ outk) {
    int row = blockIdx.y;                    // b*2048 + l
    int p = blockIdx.x * 256 + threadIdx.x;  // 0..2559: 32 q-heads + 8 kv-heads, 64 pairs each
    int b = row >> 11, l = row & 2047;
    float freq = exp2f((float)(p & 63) * -0.2076205059304601f);  // 10000^(-i/64)
    float sv, cv; sincosf((float)l * freq, &sv, &cv);
    if (p < 2048) {
        int h = p >> 6, i = p & 63;
        size_t idx = (size_t)row * 6144 + h * 128 + 2 * i;
        u32 pr = *(const u32*)(qkv + idx);
        float x1 = b2f((u16)(pr & 0xffff)), x2 = b2f((u16)(pr >> 16));
        float o1 = x1 * cv + x2 * sv, o2 = x1 * sv - x2 * cv;
        *(u32*)(qkv + idx) = (u32)f2b(o1) | ((u32)f2b(o2) << 16);
    } else {
        int kvh = (p >> 6) - 32, i = p & 63;
        size_t idx = (size_t)row * 6144 + 4096 + kvh * 128 + 2 * i;
        u32 pr = *(const u32*)(qkv + idx);
        float x1 = b2f((u16)(pr & 0xffff)), x2 = b2f((u16)(pr >> 16));
        float o1 = x1 * cv + x2 * sv, o2 = x1 * sv - x2 * cv;
        *(u32*)(qkv + idx) = (u32)f2b(o1) | ((u32)f2b(o2) << 16);
#pragma unroll
        for (int r = 0; r < 4; ++r) {
            float2 o; o.x = o1; o.y = o2;
            *(float2*)(outk + ((size_t)((b * 32 + kvh * 4 + r) * 2048) + l) * 128 + 2 * i) = o;
        }
    }
}

// --------------------------------- V: write f32 x4 GQA copies to d_out + bf16 V^T for attention
__global__ __launch_bounds__(256) void vtrans_kernel(const u16* __restrict__ qkv,
                                                     u16* __restrict__ vt,
                                                     float* __restrict__ outv) {
    __shared__ u16 tile[64][65];
    int t = threadIdx.x;
    int l0 = blockIdx.x * 64, d0 = blockIdx.y * 64;
    int z = blockIdx.z, b = z >> 3, kvh = z & 7;
    int r = t >> 4, c4 = (t & 15) * 4;
#pragma unroll
    for (int i = 0; i < 4; ++i) {
        int l = l0 + i * 16 + r;
        ushort4 v = *(const ushort4*)(qkv + (size_t)(b * 2048 + l) * 6144 + 5120 + kvh * 128 + d0 + c4);
        tile[i * 16 + r][c4 + 0] = v.x; tile[i * 16 + r][c4 + 1] = v.y;
        tile[i * 16 + r][c4 + 2] = v.z; tile[i * 16 + r][c4 + 3] = v.w;
        float4 f; f.x = b2f(v.x); f.y = b2f(v.y); f.z = b2f(v.z); f.w = b2f(v.w);
#pragma unroll
        for (int rr = 0; rr < 4; ++rr)
            *(float4*)(outv + ((size_t)((b * 32 + kvh * 4 + rr) * 2048) + l) * 128 + d0 + c4) = f;
    }
    __syncthreads();
#pragma unroll
    for (int i = 0; i < 4; ++i) {
        int dn = i * 16 + r;
        ushort4 o;
        o.x = tile[c4 + 0][dn]; o.y = tile[c4 + 1][dn];
        o.z = tile[c4 + 2][dn]; o.w = tile[c4 + 3][dn];
        *(ushort4*)(vt + (size_t)((b * 8 + kvh) * 128 + d0 + dn) * 2048 + l0 + c4) = o;
    }
}

// ---------------------------------------------------------------- flash attention v4.1
// 32 q-rows per wave (two 16-row halves sharing every K/V fragment read); QBLK=128/block,
// grid (8,32,2) = 512 blocks = 2/CU (LDS 80 KB). Passed r9 at absmax 0.031.
__global__ __launch_bounds__(256, 2) void attn_kernel(const u16* __restrict__ qkv,
                                                      const u16* __restrict__ vt,
                                                      u16* __restrict__ ab) {
    __shared__ __align__(16) u16 Kbuf[2][64 * 128];   // K tile [kv][dh]     32 KB
    __shared__ __align__(16) u16 Vbuf[2][128 * 64];   // V^T tile [dh][kv]   32 KB
    __shared__ __align__(16) u16 Ps[4][32 * 64];      // per-wave P [q=32][kv=64]  16 KB
    int t = threadIdx.x, lane = t & 63, w = t >> 6;
    int lr = lane & 15, hi = lane >> 4;
    int h = blockIdx.y, b = blockIdx.z, kvh = h >> 2;

    const u16* kbase = qkv + (size_t)(b * 2048) * 6144 + 4096 + kvh * 128;
    const u16* vtbase = vt + (size_t)((b * 8 + kvh) * 128) * 2048;

    auto stageKV = [&](int k0, int buf) {
#pragma unroll
        for (int i = 0; i < 4; ++i) {   // K: 64 rows x 128 cols
            int c = i * 256 + t;
            int row = c >> 4;
            int col8 = ((c & 15) ^ (row & 7)) << 3;
            gload16(kbase + (size_t)(k0 + row) * 6144 + col8,
                    (char*)Kbuf[buf] + (i * 256 + (t & ~63)) * 16);
        }
#pragma unroll
        for (int i = 0; i < 4; ++i) {   // V^T: 128 rows x 64 cols
            int c = i * 256 + t;
            int row = c >> 3;
            int col8 = ((c & 7) ^ (row & 7)) << 3;
            gload16(vtbase + (size_t)row * 2048 + k0 + col8,
                    (char*)Vbuf[buf] + (i * 256 + (t & ~63)) * 16);
        }
    };

    auto process = [&](int qblk) {
        int q0 = qblk * 128;
        bf16x8 qf[2][4];
#pragma unroll
        for (int half = 0; half < 2; ++half)
#pragma unroll
            for (int kki = 0; kki < 4; ++kki)
                qf[half][kki] = *(const bf16x8*)(qkv +
                    (size_t)(b * 2048 + q0 + w * 32 + half * 16 + lr) * 6144 + h * 128 +
                    kki * 32 + 8 * hi);
        f32x4 acc[2][8] = {};
        float mrun[2] = {-1e30f, -1e30f}, lrun[2] = {0.f, 0.f};

        int nt = 2 * (qblk + 1);
        stageKV(0, 0);
        __syncthreads();
        int cur = 0;
        for (int kt = 0; kt < nt; ++kt) {
            if (kt + 1 < nt) stageKV((kt + 1) * 64, cur ^ 1);  // prefetch next tile
            __builtin_amdgcn_sched_barrier(0);

            const u16* Ks = Kbuf[cur];
            const u16* Vs = Vbuf[cur];
            // S^T = K Q^T for both halves, sharing each kf read
            f32x4 s[2][4] = {};
            __builtin_amdgcn_s_setprio(1);
#pragma unroll
            for (int kki = 0; kki < 4; ++kki) {
                bf16x8 kf[4];
#pragma unroll
                for (int fc = 0; fc < 4; ++fc) {
                    int kvr = fc * 16 + lr;
                    int byt = (kvr * 256 + (kki * 32 + 8 * hi) * 2) ^ ((kvr & 7) << 4);
                    kf[fc] = *(const bf16x8*)((const char*)Ks + byt);
                }
#pragma unroll
                for (int fc = 0; fc < 4; ++fc) {
                    s[0][fc] = mfma16(kf[fc], qf[0][kki], s[0][fc]);
                    s[1][fc] = mfma16(kf[fc], qf[1][kki], s[1][fc]);
                }
            }
            __builtin_amdgcn_s_setprio(0);
            const float SC = 0.08838834764831845f;  // 1/sqrt(128)
            int domask = (kt >= nt - 2);
            u16* Pw = Ps[w];
#pragma unroll
            for (int half = 0; half < 2; ++half) {
                int qabs = q0 + w * 32 + half * 16 + lr;
#pragma unroll
                for (int fc = 0; fc < 4; ++fc)
#pragma unroll
                    for (int r = 0; r < 4; ++r) {
                        float v = s[half][fc][r] * SC;
                        if (domask && (kt * 64 + fc * 16 + hi * 4 + r) > qabs) v = -1e30f;
                        s[half][fc][r] = v;
                    }
                // online softmax, scalar per lane (one q-row per half)
                float pm = s[half][0][0];
#pragma unroll
                for (int fc = 0; fc < 4; ++fc)
#pragma unroll
                    for (int r = 0; r < 4; ++r) pm = fmaxf(pm, s[half][fc][r]);
                pm = fmaxf(pm, __shfl_xor(pm, 16));
                pm = fmaxf(pm, __shfl_xor(pm, 32));
                float mn = fmaxf(mrun[half], pm);
                float fr = __expf(mrun[half] - mn);
                mrun[half] = mn;
                float ls = 0.f;
#pragma unroll
                for (int fc = 0; fc < 4; ++fc)
#pragma unroll
                    for (int r = 0; r < 4; ++r) {
                        float e = __expf(s[half][fc][r] - mn);
                        s[half][fc][r] = e;
                        ls += e;
                    }
                ls += __shfl_xor(ls, 16);
                ls += __shfl_xor(ls, 32);
                lrun[half] = lrun[half] * fr + ls;
#pragma unroll
                for (int dhf = 0; dhf < 8; ++dhf)
#pragma unroll
                    for (int r = 0; r < 4; ++r) acc[half][dhf][r] *= fr;
                // P -> LDS: row q = half*16+lr (128 B/row -> half block at 2048 B)
#pragma unroll
                for (int fc = 0; fc < 4; ++fc) {
                    u32x2 pk;
                    pk.x = (u32)f2b(s[half][fc][0]) | ((u32)f2b(s[half][fc][1]) << 16);
                    pk.y = (u32)f2b(s[half][fc][2]) | ((u32)f2b(s[half][fc][3]) << 16);
                    int byt = (half * 2048 + lr * 128 + fc * 32 + hi * 8) ^ ((lr & 7) << 4);
                    *(u32x2*)((char*)Pw + byt) = pk;
                }
            }
            asm volatile("s_waitcnt lgkmcnt(0)" ::: "memory");
            // O^T += V^T P^T; each vf read shared by both halves
            __builtin_amdgcn_s_setprio(1);
#pragma unroll
            for (int kk2 = 0; kk2 < 2; ++kk2) {
                bf16x8 pf0 = *(const bf16x8*)((const char*)Pw +
                    ((lr * 128 + kk2 * 64 + hi * 16) ^ ((lr & 7) << 4)));
                bf16x8 pf1 = *(const bf16x8*)((const char*)Pw +
                    ((2048 + lr * 128 + kk2 * 64 + hi * 16) ^ ((lr & 7) << 4)));
#pragma unroll
                for (int dhf = 0; dhf < 8; ++dhf) {
                    int dh = dhf * 16 + lr;
                    int bytv = (dh * 128 + (kk2 * 32 + 8 * hi) * 2) ^ ((dh & 7) << 4);
                    bf16x8 vf = *(const bf16x8*)((const char*)Vs + bytv);
                    acc[0][dhf] = mfma16(vf, pf0, acc[0][dhf]);
                    acc[1][dhf] = mfma16(vf, pf1, acc[1][dhf]);
                }
            }
            __builtin_amdgcn_s_setprio(0);
            __syncthreads();   // drains vmcnt -> prefetched tile ready; buf[cur] reads retired
            cur ^= 1;
        }
        // epilogue
#pragma unroll
        for (int half = 0; half < 2; ++half) {
            float inv = 1.0f / lrun[half];
            int qrow = q0 + w * 32 + half * 16 + lr;
#pragma unroll
            for (int dhf = 0; dhf < 8; ++dhf) {
                ushort4 o;
                o.x = f2b(acc[half][dhf][0] * inv); o.y = f2b(acc[half][dhf][1] * inv);
                o.z = f2b(acc[half][dhf][2] * inv); o.w = f2b(acc[half][dhf][3] * inv);
                *(ushort4*)(ab + (size_t)(b * 2048 + qrow) * 4096 + h * 128 + dhf * 16 + hi * 4) = o;
            }
        }
    };

    process(15 - blockIdx.x);   // long tile first
    __syncthreads();
    process(blockIdx.x);
}

// ---------------------------------------------------------------- launch
extern "C" void kernel_launch(void* const* d_in, const int* in_sizes, int n_in,
                              void* d_out, int out_size, void* d_ws, size_t ws_size,
                              hipStream_t stream) {
    (void)in_sizes; (void)n_in; (void)out_size; (void)ws_size;
    const float* x  = (const float*)d_in[0];
    // d_in[1] = mask: exact causal tril(0 / -1e9) — handled analytically in attn_kernel
    const float* wq = (const float*)d_in[2];
    const float* wk = (const float*)d_in[3];
    const float* wv = (const float*)d_in[4];
    const float* wo = (const float*)d_in[5];

    char* ws = (char*)d_ws;
    u16* xb  = (u16*)(ws + 0);                       // 32 MiB; reused as ab after QKV GEMM
    u16* fBt = (u16*)(ws + 33554432);                // 48 MiB fused [wq^T; wk^T; wv^T]
    u16* qkv = (u16*)(ws + 83886080);                // 48 MiB [4096][6144]
    u16* vt  = (u16*)(ws + 134217728);               //  8 MiB -> total 142 MiB
    u16* ab  = xb;
    u16* wob = fBt;                                  // reuse fBt region after QKV GEMM

    float* out0 = (float*)d_out;
    float* outk = out0 + 16777216;
    float* outv = out0 + 33554432;

    convx_kernel<<<16384, 256, 0, stream>>>(x, xb);
    tconv_kernel<<<dim3(64, 64), 256, 0, stream>>>(wq, fBt, 4096, 4096);
    tconv_kernel<<<dim3(16, 64), 256, 0, stream>>>(wk, fBt + (size_t)4096 * 4096, 4096, 1024);
    tconv_kernel<<<dim3(16, 64), 256, 0, stream>>>(wv, fBt + (size_t)5120 * 4096, 4096, 1024);

    // fused QKV projection: 128x128 tiles, grid 48x32 = 1536 blocks = 3 rounds at 2/CU
    gemm128_kernel<false><<<1536, 256, 0, stream>>>(xb, fBt, qkv, nullptr, 6144, 4096, 32);

    tconv_kernel<<<dim3(64, 64), 256, 0, stream>>>(wo, wob, 4096, 4096);  // fBt dead now

    rope_kernel<<<dim3(10, 4096), 256, 0, stream>>>(qkv, outk);
    vtrans_kernel<<<dim3(32, 2, 16), 256, 0, stream>>>(qkv, vt, outv);

    attn_kernel<<<dim3(8, 32, 2), 256, 0, stream>>>(qkv, vt, ab);

    // output projection: 128x128 tiles, grid 32x32 = 1024 blocks = 2 rounds at 2/CU
    gemm128_kernel<true><<<1024, 256, 0, stream>>>(ab, wob, nullptr, out0, 4096, 4096, 32);
}